// Round 3
// baseline (186.171 us; speedup 1.0000x reference)
//
#include <hip/hip_runtime.h>
#include <hip/hip_bf16.h>
#include <stdint.h>

// Problem constants
#define BB 4
#define CC 128
#define NN 4096
#define NSEG 8
#define SEGLEN (NN / NSEG)   // 512
#define KVBLK 64

typedef __bf16 bf16_t;
typedef bf16_t bf16x8 __attribute__((ext_vector_type(8)));
typedef float f32x4 __attribute__((ext_vector_type(4)));
typedef float f32x16 __attribute__((ext_vector_type(16)));
typedef int v2i __attribute__((ext_vector_type(2)));
typedef unsigned int u32;
typedef unsigned short u16;

__device__ __forceinline__ u16 f2bf(float f) {
  union { float f; u32 u; } v; v.f = f;
  u32 r = v.u + 0x7FFFu + ((v.u >> 16) & 1u);   // RNE
  return (u16)(r >> 16);
}
__device__ __forceinline__ float bf2f(u16 x) {
  union { u32 u; float f; } v; v.u = ((u32)x) << 16; return v.f;
}

__device__ __forceinline__ bf16x8 ldfrag(const u16* p) {
  return *reinterpret_cast<const bf16x8*>(p);   // ds_read_b128
}

__device__ __forceinline__ f32x4 mfma16(bf16x8 a, bf16x8 b, f32x4 c) {
  return __builtin_amdgcn_mfma_f32_16x16x32_bf16(a, b, c, 0, 0, 0);
}
__device__ __forceinline__ f32x16 mfma32(bf16x8 a, bf16x8 b, f32x16 c) {
  return __builtin_amdgcn_mfma_f32_32x32x16_bf16(a, b, c, 0, 0, 0);
}
__device__ __forceinline__ u32 cvtpk(float lo, float hi) {
  u32 d; asm("v_cvt_pk_bf16_f32 %0, %1, %2" : "=v"(d) : "v"(lo), "v"(hi)); return d;
}

// ---------------------------------------------------------------------------
// Kernel 1: projections (unchanged).
//   p=0: theta -> qws [B][N][C];  p=1: phi -> kws [B][N][C];  p=2: g -> vws [B][C][N]
// ---------------------------------------------------------------------------
__global__ __launch_bounds__(256) void proj_kernel(
    const float* __restrict__ x0, const float* __restrict__ x1,
    const float* __restrict__ g_w, const float* __restrict__ g_b,
    const float* __restrict__ th_w, const float* __restrict__ th_b,
    const float* __restrict__ ph_w, const float* __restrict__ ph_b,
    u16* __restrict__ qws, u16* __restrict__ kws, u16* __restrict__ vws)
{
  const int t = threadIdx.x;
  const int nt0 = blockIdx.x * 64;
  const int b = blockIdx.y;
  const int p = blockIdx.z;

  __shared__ __align__(16) u16 W_lds[128][136];
  __shared__ __align__(16) u16 xT_lds[64][136];

  const float* x    = (p == 0) ? x1 : x0;
  const float* w    = (p == 0) ? th_w : (p == 1) ? ph_w : g_w;
  const float* bias = (p == 0) ? th_b : (p == 1) ? ph_b : g_b;

  for (int i = 0; i < 16; ++i) {
    int s = t + i * 256;
    int row = s >> 5, c4 = s & 31;
    float4 v = *reinterpret_cast<const float4*>(w + row * 128 + c4 * 4);
    u32 lo = (u32)f2bf(v.x) | ((u32)f2bf(v.y) << 16);
    u32 hi = (u32)f2bf(v.z) | ((u32)f2bf(v.w) << 16);
    *reinterpret_cast<uint2*>(&W_lds[row][c4 * 4]) = make_uint2(lo, hi);
  }
  for (int i = 0; i < 8; ++i) {
    int s = t + i * 256;
    int cp = s >> 4;
    int nc = s & 15;
    float4 v = *reinterpret_cast<const float4*>(x + ((size_t)b * CC + cp) * NN + nt0 + nc * 4);
    xT_lds[nc * 4 + 0][cp] = f2bf(v.x);
    xT_lds[nc * 4 + 1][cp] = f2bf(v.y);
    xT_lds[nc * 4 + 2][cp] = f2bf(v.z);
    xT_lds[nc * 4 + 3][cp] = f2bf(v.w);
  }
  __syncthreads();

  const int w_id = t >> 6, l = t & 63;
  const int lr = l & 15, lh = l >> 4;

  if (p < 2) {
    f32x4 acc[8];
#pragma unroll
    for (int ct = 0; ct < 8; ++ct) acc[ct] = (f32x4){0.f, 0.f, 0.f, 0.f};
#pragma unroll
    for (int kc = 0; kc < 4; ++kc) {
      bf16x8 a = ldfrag(&xT_lds[w_id * 16 + lr][kc * 32 + lh * 8]);
#pragma unroll
      for (int ct = 0; ct < 8; ++ct) {
        bf16x8 bf = ldfrag(&W_lds[ct * 16 + lr][kc * 32 + lh * 8]);
        acc[ct] = mfma16(a, bf, acc[ct]);
      }
    }
    u16* outp = (p == 0) ? qws : kws;
#pragma unroll
    for (int ct = 0; ct < 8; ++ct) {
      float bv = bias[ct * 16 + lr];
#pragma unroll
      for (int r = 0; r < 4; ++r) {
        int n = nt0 + w_id * 16 + lh * 4 + r;
        outp[((size_t)b * NN + n) * CC + ct * 16 + lr] = f2bf(acc[ct][r] + bv);
      }
    }
  } else {
    f32x4 acc[2][4];
#pragma unroll
    for (int rt = 0; rt < 2; ++rt)
#pragma unroll
      for (int nt = 0; nt < 4; ++nt) acc[rt][nt] = (f32x4){0.f, 0.f, 0.f, 0.f};
#pragma unroll
    for (int kc = 0; kc < 4; ++kc) {
      bf16x8 a0 = ldfrag(&W_lds[w_id * 32 + lr][kc * 32 + lh * 8]);
      bf16x8 a1 = ldfrag(&W_lds[w_id * 32 + 16 + lr][kc * 32 + lh * 8]);
#pragma unroll
      for (int nt = 0; nt < 4; ++nt) {
        bf16x8 bf = ldfrag(&xT_lds[nt * 16 + lr][kc * 32 + lh * 8]);
        acc[0][nt] = mfma16(a0, bf, acc[0][nt]);
        acc[1][nt] = mfma16(a1, bf, acc[1][nt]);
      }
    }
#pragma unroll
    for (int rt = 0; rt < 2; ++rt)
#pragma unroll
      for (int r = 0; r < 4; ++r) {
        int c = w_id * 32 + rt * 16 + lh * 4 + r;
        float bv = bias[c];
#pragma unroll
        for (int nt = 0; nt < 4; ++nt) {
          vws[((size_t)b * CC + c) * NN + nt0 + nt * 16 + lr] = f2bf(acc[rt][nt][r] + bv);
        }
      }
  }
}

// ---------------------------------------------------------------------------
// Kernel 2: flash attention, 32x32 MFMA, swapped-QK^T, in-register softmax.
// NSEG=8 KV-split, 1024 blocks, XCD-bijective swizzle, 4 blocks/CU.
// Partials stored l-normalized in bf16.
// ---------------------------------------------------------------------------
__global__ __launch_bounds__(256, 4) void attn_kernel(
    const u16* __restrict__ qws, const u16* __restrict__ kws,
    const u16* __restrict__ vws, u16* __restrict__ yacc,
    float* __restrict__ ml)
{
  const int t = threadIdx.x, wv = t >> 6, l = t & 63;
  const int l31 = l & 31, hi = l >> 5;
  // XCD-bijective swizzle: 1024 blocks, 8 XCDs, 128 each; same (b,seg) contiguous per XCD
  const int bid = blockIdx.x;
  const int id  = (bid & 7) * 128 + (bid >> 3);
  const int qb = id & 31, grp = id >> 5;
  const int b = grp >> 3, seg = grp & 7;
  const int q0 = qb * 128;
  constexpr int NCH = SEGLEN / KVBLK;   // 8

  __shared__ __align__(16) u16 K_lds[64][128];    // [key][c], XOR-16 swizzled
  __shared__ __align__(16) u16 Vt_lds[128][72];   // [c][key], pad

  // Q fragments: lane holds Q[q=l31][kc*16 + hi*8 .. +7] for kc=0..7
  bf16x8 qf[8];
  {
    const u16* qp = qws + ((size_t)b * NN + q0 + wv * 32 + l31) * CC + hi * 8;
#pragma unroll
    for (int kc = 0; kc < 8; ++kc) qf[kc] = *reinterpret_cast<const bf16x8*>(qp + kc * 16);
  }

  // staging geometry
  int kr[4], kc8[4], vc[4], vm8[4];
#pragma unroll
  for (int i = 0; i < 4; ++i) {
    int s = t + i * 256;
    kr[i] = s >> 4; kc8[i] = (s & 15) * 8;
    vc[i] = s >> 3; vm8[i] = (s & 7) * 8;
  }
  const u16* kg = kws + ((size_t)b * NN + seg * SEGLEN) * CC;
  const u16* vg = vws + (size_t)b * CC * NN + seg * SEGLEN;
  uint4 kreg[4], vreg[4];
#pragma unroll
  for (int i = 0; i < 4; ++i) kreg[i] = *reinterpret_cast<const uint4*>(kg + (size_t)kr[i] * CC + kc8[i]);
#pragma unroll
  for (int i = 0; i < 4; ++i) vreg[i] = *reinterpret_cast<const uint4*>(vg + (size_t)vc[i] * NN + vm8[i]);

  f32x16 yt[4];
#pragma unroll
  for (int ct = 0; ct < 4; ++ct)
#pragma unroll
    for (int r = 0; r < 16; ++r) yt[ct][r] = 0.f;
  float m_run = -1e30f, l_run = 0.f;

  for (int ch = 0; ch < NCH; ++ch) {
    __syncthreads();
#pragma unroll
    for (int i = 0; i < 4; ++i)
      *reinterpret_cast<uint4*>(&K_lds[kr[i]][kc8[i] ^ ((kr[i] & 15) * 8)]) = kreg[i];
#pragma unroll
    for (int i = 0; i < 4; ++i) *reinterpret_cast<uint4*>(&Vt_lds[vc[i]][vm8[i]]) = vreg[i];
    if (ch + 1 < NCH) {   // prefetch next chunk under compute
      kg += KVBLK * CC; vg += KVBLK;
#pragma unroll
      for (int i = 0; i < 4; ++i) kreg[i] = *reinterpret_cast<const uint4*>(kg + (size_t)kr[i] * CC + kc8[i]);
#pragma unroll
      for (int i = 0; i < 4; ++i) vreg[i] = *reinterpret_cast<const uint4*>(vg + (size_t)vc[i] * NN + vm8[i]);
    }
    __syncthreads();

    // --- swapped QK^T
    f32x16 st0, st1;
#pragma unroll
    for (int r = 0; r < 16; ++r) { st0[r] = 0.f; st1[r] = 0.f; }
    __builtin_amdgcn_s_setprio(1);
#pragma unroll
    for (int kc = 0; kc < 8; ++kc) {
      bf16x8 a0 = ldfrag(&K_lds[l31][(kc * 16 + hi * 8) ^ ((l31 & 15) * 8)]);
      bf16x8 a1 = ldfrag(&K_lds[32 + l31][(kc * 16 + hi * 8) ^ ((l31 & 15) * 8)]);
      st0 = mfma32(a0, qf[kc], st0);
      st1 = mfma32(a1, qf[kc], st1);
    }
    __builtin_amdgcn_s_setprio(0);

    // --- online softmax, tree reductions
    float tm[16];
#pragma unroll
    for (int i = 0; i < 16; ++i) tm[i] = fmaxf(st0[i], st1[i]);
#pragma unroll
    for (int i = 0; i < 8; ++i) tm[i] = fmaxf(tm[i], tm[i + 8]);
#pragma unroll
    for (int i = 0; i < 4; ++i) tm[i] = fmaxf(tm[i], tm[i + 4]);
    float mx = fmaxf(fmaxf(tm[0], tm[1]), fmaxf(tm[2], tm[3]));
    {
      v2i rr = __builtin_amdgcn_permlane32_swap(__float_as_int(mx), __float_as_int(mx), false, false);
      mx = fmaxf(__int_as_float(rr.x), __int_as_float(rr.y));
    }
    if (!__all(mx - m_run <= 8.f)) {   // defer-max
      float mnew = fmaxf(m_run, mx);
      float sc = __expf(m_run - mnew);
      l_run *= sc;
#pragma unroll
      for (int ct = 0; ct < 4; ++ct)
#pragma unroll
        for (int r = 0; r < 16; ++r) yt[ct][r] *= sc;
      m_run = mnew;
    }
#pragma unroll
    for (int r = 0; r < 16; ++r) st0[r] = __expf(st0[r] - m_run);
#pragma unroll
    for (int r = 0; r < 16; ++r) st1[r] = __expf(st1[r] - m_run);
    float ts[16];
#pragma unroll
    for (int i = 0; i < 16; ++i) ts[i] = st0[i] + st1[i];
#pragma unroll
    for (int i = 0; i < 8; ++i) ts[i] = ts[i] + ts[i + 8];
#pragma unroll
    for (int i = 0; i < 4; ++i) ts[i] = ts[i] + ts[i + 4];
    float ps = (ts[0] + ts[1]) + (ts[2] + ts[3]);
    {
      v2i rr = __builtin_amdgcn_permlane32_swap(__float_as_int(ps), __float_as_int(ps), false, false);
      ps = __int_as_float(rr.x) + __int_as_float(rr.y);
    }
    l_run += ps;

    // --- PV via cvt_pk + permlane32_swap (T12)
    __builtin_amdgcn_s_setprio(1);
#define PV_KC2(SS, KC2) do {                                                        \
      u32 X0 = cvtpk(SS[(((KC2)&1)*8)+0], SS[(((KC2)&1)*8)+1]);                     \
      u32 X1 = cvtpk(SS[(((KC2)&1)*8)+2], SS[(((KC2)&1)*8)+3]);                     \
      u32 X4 = cvtpk(SS[(((KC2)&1)*8)+4], SS[(((KC2)&1)*8)+5]);                     \
      u32 X5 = cvtpk(SS[(((KC2)&1)*8)+6], SS[(((KC2)&1)*8)+7]);                     \
      v2i s1 = __builtin_amdgcn_permlane32_swap((int)X0, (int)X4, false, false);    \
      v2i s2 = __builtin_amdgcn_permlane32_swap((int)X1, (int)X5, false, false);    \
      int4 bw = make_int4(s1.x, s2.x, s1.y, s2.y);                                  \
      bf16x8 pb = *reinterpret_cast<bf16x8*>(&bw);                                  \
      _Pragma("unroll")                                                             \
      for (int ct = 0; ct < 4; ++ct) {                                              \
        bf16x8 va = ldfrag(&Vt_lds[ct * 32 + l31][(KC2) * 16 + hi * 8]);            \
        yt[ct] = mfma32(va, pb, yt[ct]);                                            \
      }                                                                             \
    } while (0)
    PV_KC2(st0, 0);
    PV_KC2(st0, 1);
    PV_KC2(st1, 2);
    PV_KC2(st1, 3);
#undef PV_KC2
    __builtin_amdgcn_s_setprio(0);
  }

  // epilogue: l-normalized bf16 partials -> yacc [b*NSEG+seg][q][c]
  const float inv_l = 1.0f / l_run;
  const size_t row_g = (size_t)(b * NSEG + seg) * NN + q0 + wv * 32 + l31;
  u16* yp = yacc + row_g * CC;
#pragma unroll
  for (int ct = 0; ct < 4; ++ct)
#pragma unroll
    for (int g = 0; g < 4; ++g) {
      u32 w0 = cvtpk(yt[ct][4 * g + 0] * inv_l, yt[ct][4 * g + 1] * inv_l);
      u32 w1 = cvtpk(yt[ct][4 * g + 2] * inv_l, yt[ct][4 * g + 3] * inv_l);
      *reinterpret_cast<uint2*>(yp + ct * 32 + g * 8 + hi * 4) = make_uint2(w0, w1);
    }
  if (l < 32) {
    ml[row_g * 2 + 0] = m_run;
    ml[row_g * 2 + 1] = l_run;
  }
}

// ---------------------------------------------------------------------------
// Kernel 3: fused combine + out-projection.
// Stage y-tile from 8 bf16 partials (weighted by e^{m_s-M} l_s), then GEMM.
// out f32 [B][C][N]
// ---------------------------------------------------------------------------
__global__ __launch_bounds__(256) void outproj_kernel(
    const u16* __restrict__ yacc, const float* __restrict__ ml,
    const float* __restrict__ Ww, const float* __restrict__ Wb,
    float* __restrict__ out)
{
  const int t = threadIdx.x;
  const int nt0 = blockIdx.x * 64;
  const int b = blockIdx.y;

  __shared__ __align__(16) u16 W_lds[128][136];
  __shared__ __align__(16) u16 y_lds[64][136];

  for (int i = 0; i < 16; ++i) {
    int s = t + i * 256;
    int row = s >> 5, c4 = s & 31;
    float4 v = *reinterpret_cast<const float4*>(Ww + row * 128 + c4 * 4);
    u32 lo = (u32)f2bf(v.x) | ((u32)f2bf(v.y) << 16);
    u32 hi = (u32)f2bf(v.z) | ((u32)f2bf(v.w) << 16);
    *reinterpret_cast<uint2*>(&W_lds[row][c4 * 4]) = make_uint2(lo, hi);
  }
  // combine 8 segments while staging y
#pragma unroll
  for (int pass = 0; pass < 4; ++pass) {
    int row = pass * 16 + (t >> 4);
    int li = t & 15;
    int n = nt0 + row;
    float m_s[NSEG], l_s[NSEG];
#pragma unroll
    for (int s = 0; s < NSEG; ++s) {
      size_t rg = ((size_t)(b * NSEG + s) * NN + n);
      m_s[s] = ml[rg * 2];
      l_s[s] = ml[rg * 2 + 1];
    }
    float tm[4];
#pragma unroll
    for (int i = 0; i < 4; ++i) tm[i] = fmaxf(m_s[i], m_s[i + 4]);
    float M = fmaxf(fmaxf(tm[0], tm[1]), fmaxf(tm[2], tm[3]));
    float wgt[NSEG], Wsum = 0.f;
#pragma unroll
    for (int s = 0; s < NSEG; ++s) { wgt[s] = __expf(m_s[s] - M) * l_s[s]; Wsum += wgt[s]; }
    float inv = 1.0f / Wsum;
    float o[8];
#pragma unroll
    for (int j = 0; j < 8; ++j) o[j] = 0.f;
#pragma unroll
    for (int s = 0; s < NSEG; ++s) {
      uint4 v = *reinterpret_cast<const uint4*>(
          yacc + ((size_t)(b * NSEG + s) * NN + n) * CC + li * 8);
      const u16* h = reinterpret_cast<const u16*>(&v);
      float w = wgt[s];
#pragma unroll
      for (int j = 0; j < 8; ++j) o[j] += w * bf2f(h[j]);
    }
    u32 p0 = (u32)f2bf(o[0] * inv) | ((u32)f2bf(o[1] * inv) << 16);
    u32 p1 = (u32)f2bf(o[2] * inv) | ((u32)f2bf(o[3] * inv) << 16);
    u32 p2 = (u32)f2bf(o[4] * inv) | ((u32)f2bf(o[5] * inv) << 16);
    u32 p3 = (u32)f2bf(o[6] * inv) | ((u32)f2bf(o[7] * inv) << 16);
    *reinterpret_cast<uint4*>(&y_lds[row][li * 8]) = make_uint4(p0, p1, p2, p3);
  }
  __syncthreads();

  const int w_id = t >> 6, l = t & 63;
  const int lr = l & 15, lh = l >> 4;

  f32x4 acc[2][4];
#pragma unroll
  for (int rt = 0; rt < 2; ++rt)
#pragma unroll
    for (int nt = 0; nt < 4; ++nt) acc[rt][nt] = (f32x4){0.f, 0.f, 0.f, 0.f};
#pragma unroll
  for (int kc = 0; kc < 4; ++kc) {
    bf16x8 a0 = ldfrag(&W_lds[w_id * 32 + lr][kc * 32 + lh * 8]);
    bf16x8 a1 = ldfrag(&W_lds[w_id * 32 + 16 + lr][kc * 32 + lh * 8]);
#pragma unroll
    for (int nt = 0; nt < 4; ++nt) {
      bf16x8 bf = ldfrag(&y_lds[nt * 16 + lr][kc * 32 + lh * 8]);
      acc[0][nt] = mfma16(a0, bf, acc[0][nt]);
      acc[1][nt] = mfma16(a1, bf, acc[1][nt]);
    }
  }
#pragma unroll
  for (int rt = 0; rt < 2; ++rt)
#pragma unroll
    for (int r = 0; r < 4; ++r) {
      int c = w_id * 32 + rt * 16 + lh * 4 + r;
      float bv = Wb[c];
#pragma unroll
      for (int nt = 0; nt < 4; ++nt)
        out[((size_t)b * CC + c) * NN + nt0 + nt * 16 + lr] = acc[rt][nt][r] + bv;
    }
}

// ---------------------------------------------------------------------------
extern "C" void kernel_launch(void* const* d_in, const int* in_sizes, int n_in,
                              void* d_out, int out_size, void* d_ws, size_t ws_size,
                              hipStream_t stream) {
  const float* x0   = (const float*)d_in[0];
  const float* x1   = (const float*)d_in[1];
  const float* g_w  = (const float*)d_in[2];
  const float* g_b  = (const float*)d_in[3];
  const float* th_w = (const float*)d_in[4];
  const float* th_b = (const float*)d_in[5];
  const float* ph_w = (const float*)d_in[6];
  const float* ph_b = (const float*)d_in[7];
  const float* Ww   = (const float*)d_in[8];
  const float* Wb   = (const float*)d_in[9];

  char* ws = (char*)d_ws;
  // layout: q(4M) k(4M) v(4M) ml(1M) yacc_bf16(32M) = 45M total
  u16* qws    = (u16*)(ws + 0);
  u16* kws    = (u16*)(ws + (size_t)4194304);
  u16* vws    = (u16*)(ws + (size_t)8388608);
  float* mlp  = (float*)(ws + (size_t)12582912);
  u16* yacc   = (u16*)(ws + (size_t)13631488);

  dim3 gp(64, 4, 3);
  proj_kernel<<<gp, 256, 0, stream>>>(x0, x1, g_w, g_b, th_w, th_b, ph_w, ph_b,
                                      qws, kws, vws);
  attn_kernel<<<1024, 256, 0, stream>>>(qws, kws, vws, yacc, mlp);
  dim3 go(64, 4);
  outproj_kernel<<<go, 256, 0, stream>>>(yacc, mlp, Ww, Wb, (float*)d_out);
}

// Round 4
// 182.020 us; speedup vs baseline: 1.0228x; 1.0228x over previous
//
#include <hip/hip_runtime.h>
#include <hip/hip_bf16.h>
#include <stdint.h>

// Problem constants
#define BB 4
#define CC 128
#define NN 4096
#define NSEG 8
#define SEGLEN (NN / NSEG)   // 512
#define KVBLK 64

typedef __bf16 bf16_t;
typedef bf16_t bf16x8 __attribute__((ext_vector_type(8)));
typedef float f32x4 __attribute__((ext_vector_type(4)));
typedef float f32x16 __attribute__((ext_vector_type(16)));
typedef int v2i __attribute__((ext_vector_type(2)));
typedef unsigned int u32;
typedef unsigned short u16;

__device__ __forceinline__ u16 f2bf(float f) {
  union { float f; u32 u; } v; v.f = f;
  u32 r = v.u + 0x7FFFu + ((v.u >> 16) & 1u);   // RNE
  return (u16)(r >> 16);
}
__device__ __forceinline__ float bf2f(u16 x) {
  union { u32 u; float f; } v; v.u = ((u32)x) << 16; return v.f;
}

__device__ __forceinline__ bf16x8 ldfrag(const u16* p) {
  return *reinterpret_cast<const bf16x8*>(p);   // ds_read_b128
}

__device__ __forceinline__ f32x4 mfma16(bf16x8 a, bf16x8 b, f32x4 c) {
  return __builtin_amdgcn_mfma_f32_16x16x32_bf16(a, b, c, 0, 0, 0);
}
__device__ __forceinline__ f32x16 mfma32(bf16x8 a, bf16x8 b, f32x16 c) {
  return __builtin_amdgcn_mfma_f32_32x32x16_bf16(a, b, c, 0, 0, 0);
}
__device__ __forceinline__ u32 cvtpk(float lo, float hi) {
  u32 d; asm("v_cvt_pk_bf16_f32 %0, %1, %2" : "=v"(d) : "v"(lo), "v"(hi)); return d;
}

// ---------------------------------------------------------------------------
// Kernel 1: projections (unchanged).
//   p=0: theta -> qws [B][N][C];  p=1: phi -> kws [B][N][C];  p=2: g -> vws [B][C][N]
// ---------------------------------------------------------------------------
__global__ __launch_bounds__(256) void proj_kernel(
    const float* __restrict__ x0, const float* __restrict__ x1,
    const float* __restrict__ g_w, const float* __restrict__ g_b,
    const float* __restrict__ th_w, const float* __restrict__ th_b,
    const float* __restrict__ ph_w, const float* __restrict__ ph_b,
    u16* __restrict__ qws, u16* __restrict__ kws, u16* __restrict__ vws)
{
  const int t = threadIdx.x;
  const int nt0 = blockIdx.x * 64;
  const int b = blockIdx.y;
  const int p = blockIdx.z;

  __shared__ __align__(16) u16 W_lds[128][136];
  __shared__ __align__(16) u16 xT_lds[64][136];

  const float* x    = (p == 0) ? x1 : x0;
  const float* w    = (p == 0) ? th_w : (p == 1) ? ph_w : g_w;
  const float* bias = (p == 0) ? th_b : (p == 1) ? ph_b : g_b;

  for (int i = 0; i < 16; ++i) {
    int s = t + i * 256;
    int row = s >> 5, c4 = s & 31;
    float4 v = *reinterpret_cast<const float4*>(w + row * 128 + c4 * 4);
    u32 lo = (u32)f2bf(v.x) | ((u32)f2bf(v.y) << 16);
    u32 hi = (u32)f2bf(v.z) | ((u32)f2bf(v.w) << 16);
    *reinterpret_cast<uint2*>(&W_lds[row][c4 * 4]) = make_uint2(lo, hi);
  }
  for (int i = 0; i < 8; ++i) {
    int s = t + i * 256;
    int cp = s >> 4;
    int nc = s & 15;
    float4 v = *reinterpret_cast<const float4*>(x + ((size_t)b * CC + cp) * NN + nt0 + nc * 4);
    xT_lds[nc * 4 + 0][cp] = f2bf(v.x);
    xT_lds[nc * 4 + 1][cp] = f2bf(v.y);
    xT_lds[nc * 4 + 2][cp] = f2bf(v.z);
    xT_lds[nc * 4 + 3][cp] = f2bf(v.w);
  }
  __syncthreads();

  const int w_id = t >> 6, l = t & 63;
  const int lr = l & 15, lh = l >> 4;

  if (p < 2) {
    f32x4 acc[8];
#pragma unroll
    for (int ct = 0; ct < 8; ++ct) acc[ct] = (f32x4){0.f, 0.f, 0.f, 0.f};
#pragma unroll
    for (int kc = 0; kc < 4; ++kc) {
      bf16x8 a = ldfrag(&xT_lds[w_id * 16 + lr][kc * 32 + lh * 8]);
#pragma unroll
      for (int ct = 0; ct < 8; ++ct) {
        bf16x8 bf = ldfrag(&W_lds[ct * 16 + lr][kc * 32 + lh * 8]);
        acc[ct] = mfma16(a, bf, acc[ct]);
      }
    }
    u16* outp = (p == 0) ? qws : kws;
#pragma unroll
    for (int ct = 0; ct < 8; ++ct) {
      float bv = bias[ct * 16 + lr];
#pragma unroll
      for (int r = 0; r < 4; ++r) {
        int n = nt0 + w_id * 16 + lh * 4 + r;
        outp[((size_t)b * NN + n) * CC + ct * 16 + lr] = f2bf(acc[ct][r] + bv);
      }
    }
  } else {
    f32x4 acc[2][4];
#pragma unroll
    for (int rt = 0; rt < 2; ++rt)
#pragma unroll
      for (int nt = 0; nt < 4; ++nt) acc[rt][nt] = (f32x4){0.f, 0.f, 0.f, 0.f};
#pragma unroll
    for (int kc = 0; kc < 4; ++kc) {
      bf16x8 a0 = ldfrag(&W_lds[w_id * 32 + lr][kc * 32 + lh * 8]);
      bf16x8 a1 = ldfrag(&W_lds[w_id * 32 + 16 + lr][kc * 32 + lh * 8]);
#pragma unroll
      for (int nt = 0; nt < 4; ++nt) {
        bf16x8 bf = ldfrag(&xT_lds[nt * 16 + lr][kc * 32 + lh * 8]);
        acc[0][nt] = mfma16(a0, bf, acc[0][nt]);
        acc[1][nt] = mfma16(a1, bf, acc[1][nt]);
      }
    }
#pragma unroll
    for (int rt = 0; rt < 2; ++rt)
#pragma unroll
      for (int r = 0; r < 4; ++r) {
        int c = w_id * 32 + rt * 16 + lh * 4 + r;
        float bv = bias[c];
#pragma unroll
        for (int nt = 0; nt < 4; ++nt) {
          vws[((size_t)b * CC + c) * NN + nt0 + nt * 16 + lr] = f2bf(acc[rt][nt][r] + bv);
        }
      }
  }
}

// ---------------------------------------------------------------------------
// Kernel 2: flash attention, 32x32 MFMA, swapped-QK^T, in-register softmax.
// NSEG=8 KV-split. NATURAL grid order (x=qb fastest: consecutive blocks share
// the K/V segment -> L2 locality; R3's XCD remap destroyed this, FETCH 8x).
// Epilogue: per-wave LDS transpose -> fully coalesced bf16 yacc [q][c] stores.
// ---------------------------------------------------------------------------
__global__ __launch_bounds__(256, 4) void attn_kernel(
    const u16* __restrict__ qws, const u16* __restrict__ kws,
    const u16* __restrict__ vws, u16* __restrict__ yacc,
    float* __restrict__ ml)
{
  const int t = threadIdx.x, wv = t >> 6, l = t & 63;
  const int l31 = l & 31, hi = l >> 5;
  const int q0 = blockIdx.x * 128;
  const int b = blockIdx.y, seg = blockIdx.z;
  const int grp = b * NSEG + seg;
  constexpr int NCH = SEGLEN / KVBLK;   // 8

  // one LDS pool, aliased views:
  //   K view:  [64][128] u16 (XOR-16 swizzled)
  //   Vt view: [128][72] u16
  //   epilogue: per-wave [32][136] u16 transpose buffer (4*32*136 = pool size)
  __shared__ __align__(16) u16 smem[64 * 128 + 128 * 72];   // 34816 B
  u16 (*K_lds)[128] = reinterpret_cast<u16(*)[128]>(smem);
  u16 (*Vt_lds)[72] = reinterpret_cast<u16(*)[72]>(smem + 64 * 128);

  // Q fragments: lane holds Q[q=l31][kc*16 + hi*8 .. +7] for kc=0..7
  bf16x8 qf[8];
  {
    const u16* qp = qws + ((size_t)b * NN + q0 + wv * 32 + l31) * CC + hi * 8;
#pragma unroll
    for (int kc = 0; kc < 8; ++kc) qf[kc] = *reinterpret_cast<const bf16x8*>(qp + kc * 16);
  }

  // staging geometry
  int kr[4], kc8[4], vc[4], vm8[4];
#pragma unroll
  for (int i = 0; i < 4; ++i) {
    int s = t + i * 256;
    kr[i] = s >> 4; kc8[i] = (s & 15) * 8;
    vc[i] = s >> 3; vm8[i] = (s & 7) * 8;
  }
  const u16* kg = kws + ((size_t)b * NN + seg * SEGLEN) * CC;
  const u16* vg = vws + (size_t)b * CC * NN + seg * SEGLEN;
  uint4 kreg[4], vreg[4];
#pragma unroll
  for (int i = 0; i < 4; ++i) kreg[i] = *reinterpret_cast<const uint4*>(kg + (size_t)kr[i] * CC + kc8[i]);
#pragma unroll
  for (int i = 0; i < 4; ++i) vreg[i] = *reinterpret_cast<const uint4*>(vg + (size_t)vc[i] * NN + vm8[i]);

  f32x16 yt[4];
#pragma unroll
  for (int ct = 0; ct < 4; ++ct)
#pragma unroll
    for (int r = 0; r < 16; ++r) yt[ct][r] = 0.f;
  float m_run = -1e30f, l_run = 0.f;

  for (int ch = 0; ch < NCH; ++ch) {
    __syncthreads();
#pragma unroll
    for (int i = 0; i < 4; ++i)
      *reinterpret_cast<uint4*>(&K_lds[kr[i]][kc8[i] ^ ((kr[i] & 15) * 8)]) = kreg[i];
#pragma unroll
    for (int i = 0; i < 4; ++i) *reinterpret_cast<uint4*>(&Vt_lds[vc[i]][vm8[i]]) = vreg[i];
    if (ch + 1 < NCH) {   // prefetch next chunk under compute
      kg += KVBLK * CC; vg += KVBLK;
#pragma unroll
      for (int i = 0; i < 4; ++i) kreg[i] = *reinterpret_cast<const uint4*>(kg + (size_t)kr[i] * CC + kc8[i]);
#pragma unroll
      for (int i = 0; i < 4; ++i) vreg[i] = *reinterpret_cast<const uint4*>(vg + (size_t)vc[i] * NN + vm8[i]);
    }
    __syncthreads();

    // --- swapped QK^T
    f32x16 st0, st1;
#pragma unroll
    for (int r = 0; r < 16; ++r) { st0[r] = 0.f; st1[r] = 0.f; }
    __builtin_amdgcn_s_setprio(1);
#pragma unroll
    for (int kc = 0; kc < 8; ++kc) {
      bf16x8 a0 = ldfrag(&K_lds[l31][(kc * 16 + hi * 8) ^ ((l31 & 15) * 8)]);
      bf16x8 a1 = ldfrag(&K_lds[32 + l31][(kc * 16 + hi * 8) ^ ((l31 & 15) * 8)]);
      st0 = mfma32(a0, qf[kc], st0);
      st1 = mfma32(a1, qf[kc], st1);
    }
    __builtin_amdgcn_s_setprio(0);

    // --- online softmax, tree reductions
    float tm[16];
#pragma unroll
    for (int i = 0; i < 16; ++i) tm[i] = fmaxf(st0[i], st1[i]);
#pragma unroll
    for (int i = 0; i < 8; ++i) tm[i] = fmaxf(tm[i], tm[i + 8]);
#pragma unroll
    for (int i = 0; i < 4; ++i) tm[i] = fmaxf(tm[i], tm[i + 4]);
    float mx = fmaxf(fmaxf(tm[0], tm[1]), fmaxf(tm[2], tm[3]));
    {
      v2i rr = __builtin_amdgcn_permlane32_swap(__float_as_int(mx), __float_as_int(mx), false, false);
      mx = fmaxf(__int_as_float(rr.x), __int_as_float(rr.y));
    }
    if (!__all(mx - m_run <= 8.f)) {   // defer-max
      float mnew = fmaxf(m_run, mx);
      float sc = __expf(m_run - mnew);
      l_run *= sc;
#pragma unroll
      for (int ct = 0; ct < 4; ++ct)
#pragma unroll
        for (int r = 0; r < 16; ++r) yt[ct][r] *= sc;
      m_run = mnew;
    }
#pragma unroll
    for (int r = 0; r < 16; ++r) st0[r] = __expf(st0[r] - m_run);
#pragma unroll
    for (int r = 0; r < 16; ++r) st1[r] = __expf(st1[r] - m_run);
    float ts[16];
#pragma unroll
    for (int i = 0; i < 16; ++i) ts[i] = st0[i] + st1[i];
#pragma unroll
    for (int i = 0; i < 8; ++i) ts[i] = ts[i] + ts[i + 8];
#pragma unroll
    for (int i = 0; i < 4; ++i) ts[i] = ts[i] + ts[i + 4];
    float ps = (ts[0] + ts[1]) + (ts[2] + ts[3]);
    {
      v2i rr = __builtin_amdgcn_permlane32_swap(__float_as_int(ps), __float_as_int(ps), false, false);
      ps = __int_as_float(rr.x) + __int_as_float(rr.y);
    }
    l_run += ps;

    // --- PV via cvt_pk + permlane32_swap (T12)
    __builtin_amdgcn_s_setprio(1);
#define PV_KC2(SS, KC2) do {                                                        \
      u32 X0 = cvtpk(SS[(((KC2)&1)*8)+0], SS[(((KC2)&1)*8)+1]);                     \
      u32 X1 = cvtpk(SS[(((KC2)&1)*8)+2], SS[(((KC2)&1)*8)+3]);                     \
      u32 X4 = cvtpk(SS[(((KC2)&1)*8)+4], SS[(((KC2)&1)*8)+5]);                     \
      u32 X5 = cvtpk(SS[(((KC2)&1)*8)+6], SS[(((KC2)&1)*8)+7]);                     \
      v2i s1 = __builtin_amdgcn_permlane32_swap((int)X0, (int)X4, false, false);    \
      v2i s2 = __builtin_amdgcn_permlane32_swap((int)X1, (int)X5, false, false);    \
      int4 bw = make_int4(s1.x, s2.x, s1.y, s2.y);                                  \
      bf16x8 pb = *reinterpret_cast<bf16x8*>(&bw);                                  \
      _Pragma("unroll")                                                             \
      for (int ct = 0; ct < 4; ++ct) {                                              \
        bf16x8 va = ldfrag(&Vt_lds[ct * 32 + l31][(KC2) * 16 + hi * 8]);            \
        yt[ct] = mfma32(va, pb, yt[ct]);                                            \
      }                                                                             \
    } while (0)
    PV_KC2(st0, 0);
    PV_KC2(st0, 1);
    PV_KC2(st1, 2);
    PV_KC2(st1, 3);
#undef PV_KC2
    __builtin_amdgcn_s_setprio(0);
  }

  // --- epilogue: transpose via per-wave LDS buffer, then coalesced stores.
  __syncthreads();   // all waves done reading K/Vt views
  const float inv_l = 1.0f / l_run;
  u16* eps = smem + wv * (32 * 136);   // per-wave [32 q][136 c-pitch]
#pragma unroll
  for (int ct = 0; ct < 4; ++ct)
#pragma unroll
    for (int g = 0; g < 4; ++g) {
      u32 w0 = cvtpk(yt[ct][4 * g + 0] * inv_l, yt[ct][4 * g + 1] * inv_l);
      u32 w1 = cvtpk(yt[ct][4 * g + 2] * inv_l, yt[ct][4 * g + 3] * inv_l);
      // c = ct*32 + g*8 + hi*4 + (0..3), q-row = l31
      *reinterpret_cast<uint2*>(&eps[l31 * 136 + ct * 32 + g * 8 + hi * 4]) = make_uint2(w0, w1);
    }
  __syncthreads();   // also drains lgkmcnt; cheap, once
  // read back rows and store coalesced: 4 q-rows (1 KB contiguous) per pass
  u16* yp_base = yacc + ((size_t)grp * NN + q0 + wv * 32) * CC;
#pragma unroll
  for (int pass = 0; pass < 8; ++pass) {
    int q_r = pass * 4 + (l >> 4);
    int cchunk = (l & 15) * 8;
    uint4 v = *reinterpret_cast<const uint4*>(&eps[q_r * 136 + cchunk]);
    *reinterpret_cast<uint4*>(yp_base + (size_t)q_r * CC + cchunk) = v;
  }
  if (l < 32) {
    const size_t row_g = (size_t)grp * NN + q0 + wv * 32 + l31;
    ml[row_g * 2 + 0] = m_run;
    ml[row_g * 2 + 1] = l_run;
  }
}

// ---------------------------------------------------------------------------
// Kernel 3: fused combine + out-projection.
// Stage y-tile from 8 bf16 partials (weighted by e^{m_s-M} l_s), then GEMM.
// out f32 [B][C][N]
// ---------------------------------------------------------------------------
__global__ __launch_bounds__(256) void outproj_kernel(
    const u16* __restrict__ yacc, const float* __restrict__ ml,
    const float* __restrict__ Ww, const float* __restrict__ Wb,
    float* __restrict__ out)
{
  const int t = threadIdx.x;
  const int nt0 = blockIdx.x * 64;
  const int b = blockIdx.y;

  __shared__ __align__(16) u16 W_lds[128][136];
  __shared__ __align__(16) u16 y_lds[64][136];

  for (int i = 0; i < 16; ++i) {
    int s = t + i * 256;
    int row = s >> 5, c4 = s & 31;
    float4 v = *reinterpret_cast<const float4*>(Ww + row * 128 + c4 * 4);
    u32 lo = (u32)f2bf(v.x) | ((u32)f2bf(v.y) << 16);
    u32 hi = (u32)f2bf(v.z) | ((u32)f2bf(v.w) << 16);
    *reinterpret_cast<uint2*>(&W_lds[row][c4 * 4]) = make_uint2(lo, hi);
  }
  // combine 8 segments while staging y
#pragma unroll
  for (int pass = 0; pass < 4; ++pass) {
    int row = pass * 16 + (t >> 4);
    int li = t & 15;
    int n = nt0 + row;
    float m_s[NSEG], l_s[NSEG];
#pragma unroll
    for (int s = 0; s < NSEG; ++s) {
      size_t rg = ((size_t)(b * NSEG + s) * NN + n);
      m_s[s] = ml[rg * 2];
      l_s[s] = ml[rg * 2 + 1];
    }
    float tm[4];
#pragma unroll
    for (int i = 0; i < 4; ++i) tm[i] = fmaxf(m_s[i], m_s[i + 4]);
    float M = fmaxf(fmaxf(tm[0], tm[1]), fmaxf(tm[2], tm[3]));
    float wgt[NSEG], Wsum = 0.f;
#pragma unroll
    for (int s = 0; s < NSEG; ++s) { wgt[s] = __expf(m_s[s] - M) * l_s[s]; Wsum += wgt[s]; }
    float inv = 1.0f / Wsum;
    float o[8];
#pragma unroll
    for (int j = 0; j < 8; ++j) o[j] = 0.f;
#pragma unroll
    for (int s = 0; s < NSEG; ++s) {
      uint4 v = *reinterpret_cast<const uint4*>(
          yacc + ((size_t)(b * NSEG + s) * NN + n) * CC + li * 8);
      const u16* h = reinterpret_cast<const u16*>(&v);
      float w = wgt[s];
#pragma unroll
      for (int j = 0; j < 8; ++j) o[j] += w * bf2f(h[j]);
    }
    u32 p0 = (u32)f2bf(o[0] * inv) | ((u32)f2bf(o[1] * inv) << 16);
    u32 p1 = (u32)f2bf(o[2] * inv) | ((u32)f2bf(o[3] * inv) << 16);
    u32 p2 = (u32)f2bf(o[4] * inv) | ((u32)f2bf(o[5] * inv) << 16);
    u32 p3 = (u32)f2bf(o[6] * inv) | ((u32)f2bf(o[7] * inv) << 16);
    *reinterpret_cast<uint4*>(&y_lds[row][li * 8]) = make_uint4(p0, p1, p2, p3);
  }
  __syncthreads();

  const int w_id = t >> 6, l = t & 63;
  const int lr = l & 15, lh = l >> 4;

  f32x4 acc[2][4];
#pragma unroll
  for (int rt = 0; rt < 2; ++rt)
#pragma unroll
    for (int nt = 0; nt < 4; ++nt) acc[rt][nt] = (f32x4){0.f, 0.f, 0.f, 0.f};
#pragma unroll
  for (int kc = 0; kc < 4; ++kc) {
    bf16x8 a0 = ldfrag(&W_lds[w_id * 32 + lr][kc * 32 + lh * 8]);
    bf16x8 a1 = ldfrag(&W_lds[w_id * 32 + 16 + lr][kc * 32 + lh * 8]);
#pragma unroll
    for (int nt = 0; nt < 4; ++nt) {
      bf16x8 bf = ldfrag(&y_lds[nt * 16 + lr][kc * 32 + lh * 8]);
      acc[0][nt] = mfma16(a0, bf, acc[0][nt]);
      acc[1][nt] = mfma16(a1, bf, acc[1][nt]);
    }
  }
#pragma unroll
  for (int rt = 0; rt < 2; ++rt)
#pragma unroll
    for (int r = 0; r < 4; ++r) {
      int c = w_id * 32 + rt * 16 + lh * 4 + r;
      float bv = Wb[c];
#pragma unroll
      for (int nt = 0; nt < 4; ++nt)
        out[((size_t)b * CC + c) * NN + nt0 + nt * 16 + lr] = acc[rt][nt][r] + bv;
    }
}

// ---------------------------------------------------------------------------
extern "C" void kernel_launch(void* const* d_in, const int* in_sizes, int n_in,
                              void* d_out, int out_size, void* d_ws, size_t ws_size,
                              hipStream_t stream) {
  const float* x0   = (const float*)d_in[0];
  const float* x1   = (const float*)d_in[1];
  const float* g_w  = (const float*)d_in[2];
  const float* g_b  = (const float*)d_in[3];
  const float* th_w = (const float*)d_in[4];
  const float* th_b = (const float*)d_in[5];
  const float* ph_w = (const float*)d_in[6];
  const float* ph_b = (const float*)d_in[7];
  const float* Ww   = (const float*)d_in[8];
  const float* Wb   = (const float*)d_in[9];

  char* ws = (char*)d_ws;
  // layout: q(4M) k(4M) v(4M) ml(1M) yacc_bf16(32M) = 45M total
  u16* qws    = (u16*)(ws + 0);
  u16* kws    = (u16*)(ws + (size_t)4194304);
  u16* vws    = (u16*)(ws + (size_t)8388608);
  float* mlp  = (float*)(ws + (size_t)12582912);
  u16* yacc   = (u16*)(ws + (size_t)13631488);

  dim3 gp(64, 4, 3);
  proj_kernel<<<gp, 256, 0, stream>>>(x0, x1, g_w, g_b, th_w, th_b, ph_w, ph_b,
                                      qws, kws, vws);
  dim3 ga(32, 4, NSEG);   // x fastest: consecutive blocks share K/V segment (L2 locality)
  attn_kernel<<<ga, 256, 0, stream>>>(qws, kws, vws, yacc, mlp);
  dim3 go(64, 4);
  outproj_kernel<<<go, 256, 0, stream>>>(yacc, mlp, Ww, Wb, (float*)d_out);
}

// Round 5
// 110.246 us; speedup vs baseline: 1.6887x; 1.6510x over previous
//
#include <hip/hip_runtime.h>
#include <hip/hip_bf16.h>
#include <stdint.h>

// Problem constants
#define BB 4
#define CC 128
#define NN 4096
#define NSEG 8
#define SEGLEN (NN / NSEG)   // 512
#define KVBLK 64

typedef __bf16 bf16_t;
typedef bf16_t bf16x8 __attribute__((ext_vector_type(8)));
typedef float f32x4 __attribute__((ext_vector_type(4)));
typedef float f32x16 __attribute__((ext_vector_type(16)));
typedef int v2i __attribute__((ext_vector_type(2)));
typedef unsigned int u32;
typedef unsigned short u16;

__device__ __forceinline__ u16 f2bf(float f) {
  union { float f; u32 u; } v; v.f = f;
  u32 r = v.u + 0x7FFFu + ((v.u >> 16) & 1u);   // RNE
  return (u16)(r >> 16);
}
__device__ __forceinline__ float bf2f(u16 x) {
  union { u32 u; float f; } v; v.u = ((u32)x) << 16; return v.f;
}

__device__ __forceinline__ bf16x8 ldfrag(const u16* p) {
  return *reinterpret_cast<const bf16x8*>(p);   // ds_read_b128
}

__device__ __forceinline__ f32x4 mfma16(bf16x8 a, bf16x8 b, f32x4 c) {
  return __builtin_amdgcn_mfma_f32_16x16x32_bf16(a, b, c, 0, 0, 0);
}
__device__ __forceinline__ f32x16 mfma32(bf16x8 a, bf16x8 b, f32x16 c) {
  return __builtin_amdgcn_mfma_f32_32x32x16_bf16(a, b, c, 0, 0, 0);
}
__device__ __forceinline__ u32 cvtpk(float lo, float hi) {
  u32 d; asm("v_cvt_pk_bf16_f32 %0, %1, %2" : "=v"(d) : "v"(lo), "v"(hi)); return d;
}

// ---------------------------------------------------------------------------
// Kernel 1: projections (unchanged).
//   p=0: theta -> qws [B][N][C];  p=1: phi -> kws [B][N][C];  p=2: g -> vws [B][C][N]
// ---------------------------------------------------------------------------
__global__ __launch_bounds__(256) void proj_kernel(
    const float* __restrict__ x0, const float* __restrict__ x1,
    const float* __restrict__ g_w, const float* __restrict__ g_b,
    const float* __restrict__ th_w, const float* __restrict__ th_b,
    const float* __restrict__ ph_w, const float* __restrict__ ph_b,
    u16* __restrict__ qws, u16* __restrict__ kws, u16* __restrict__ vws)
{
  const int t = threadIdx.x;
  const int nt0 = blockIdx.x * 64;
  const int b = blockIdx.y;
  const int p = blockIdx.z;

  __shared__ __align__(16) u16 W_lds[128][136];
  __shared__ __align__(16) u16 xT_lds[64][136];

  const float* x    = (p == 0) ? x1 : x0;
  const float* w    = (p == 0) ? th_w : (p == 1) ? ph_w : g_w;
  const float* bias = (p == 0) ? th_b : (p == 1) ? ph_b : g_b;

  for (int i = 0; i < 16; ++i) {
    int s = t + i * 256;
    int row = s >> 5, c4 = s & 31;
    float4 v = *reinterpret_cast<const float4*>(w + row * 128 + c4 * 4);
    u32 lo = (u32)f2bf(v.x) | ((u32)f2bf(v.y) << 16);
    u32 hi = (u32)f2bf(v.z) | ((u32)f2bf(v.w) << 16);
    *reinterpret_cast<uint2*>(&W_lds[row][c4 * 4]) = make_uint2(lo, hi);
  }
  for (int i = 0; i < 8; ++i) {
    int s = t + i * 256;
    int cp = s >> 4;
    int nc = s & 15;
    float4 v = *reinterpret_cast<const float4*>(x + ((size_t)b * CC + cp) * NN + nt0 + nc * 4);
    xT_lds[nc * 4 + 0][cp] = f2bf(v.x);
    xT_lds[nc * 4 + 1][cp] = f2bf(v.y);
    xT_lds[nc * 4 + 2][cp] = f2bf(v.z);
    xT_lds[nc * 4 + 3][cp] = f2bf(v.w);
  }
  __syncthreads();

  const int w_id = t >> 6, l = t & 63;
  const int lr = l & 15, lh = l >> 4;

  if (p < 2) {
    f32x4 acc[8];
#pragma unroll
    for (int ct = 0; ct < 8; ++ct) acc[ct] = (f32x4){0.f, 0.f, 0.f, 0.f};
#pragma unroll
    for (int kc = 0; kc < 4; ++kc) {
      bf16x8 a = ldfrag(&xT_lds[w_id * 16 + lr][kc * 32 + lh * 8]);
#pragma unroll
      for (int ct = 0; ct < 8; ++ct) {
        bf16x8 bf = ldfrag(&W_lds[ct * 16 + lr][kc * 32 + lh * 8]);
        acc[ct] = mfma16(a, bf, acc[ct]);
      }
    }
    u16* outp = (p == 0) ? qws : kws;
#pragma unroll
    for (int ct = 0; ct < 8; ++ct) {
      float bv = bias[ct * 16 + lr];
#pragma unroll
      for (int r = 0; r < 4; ++r) {
        int n = nt0 + w_id * 16 + lh * 4 + r;
        outp[((size_t)b * NN + n) * CC + ct * 16 + lr] = f2bf(acc[ct][r] + bv);
      }
    }
  } else {
    f32x4 acc[2][4];
#pragma unroll
    for (int rt = 0; rt < 2; ++rt)
#pragma unroll
      for (int nt = 0; nt < 4; ++nt) acc[rt][nt] = (f32x4){0.f, 0.f, 0.f, 0.f};
#pragma unroll
    for (int kc = 0; kc < 4; ++kc) {
      bf16x8 a0 = ldfrag(&W_lds[w_id * 32 + lr][kc * 32 + lh * 8]);
      bf16x8 a1 = ldfrag(&W_lds[w_id * 32 + 16 + lr][kc * 32 + lh * 8]);
#pragma unroll
      for (int nt = 0; nt < 4; ++nt) {
        bf16x8 bf = ldfrag(&xT_lds[nt * 16 + lr][kc * 32 + lh * 8]);
        acc[0][nt] = mfma16(a0, bf, acc[0][nt]);
        acc[1][nt] = mfma16(a1, bf, acc[1][nt]);
      }
    }
#pragma unroll
    for (int rt = 0; rt < 2; ++rt)
#pragma unroll
      for (int r = 0; r < 4; ++r) {
        int c = w_id * 32 + rt * 16 + lh * 4 + r;
        float bv = bias[c];
#pragma unroll
        for (int nt = 0; nt < 4; ++nt) {
          vws[((size_t)b * CC + c) * NN + nt0 + nt * 16 + lr] = f2bf(acc[rt][nt][r] + bv);
        }
      }
  }
}

// ---------------------------------------------------------------------------
// Kernel 2: flash attention, 32x32 MFMA, swapped-QK^T, in-register softmax.
// NSEG=8 KV-split, 1024 blocks, natural grid order (x=qb fastest).
// __launch_bounds__(256,2): NO forced 4 waves/SIMD — R3/R4's (256,4) forced
// ~40 regs of scratch spill (VGPR 164->64) = ~670 MB of spill traffic.
// Actual allocation ~164 unified regs -> HW fits 3 blocks/CU (12 waves/CU).
// ---------------------------------------------------------------------------
__global__ __launch_bounds__(256, 2) void attn_kernel(
    const u16* __restrict__ qws, const u16* __restrict__ kws,
    const u16* __restrict__ vws, u16* __restrict__ yacc,
    float* __restrict__ ml)
{
  const int t = threadIdx.x, wv = t >> 6, l = t & 63;
  const int l31 = l & 31, hi = l >> 5;
  const int q0 = blockIdx.x * 128;
  const int b = blockIdx.y, seg = blockIdx.z;
  const int grp = b * NSEG + seg;
  constexpr int NCH = SEGLEN / KVBLK;   // 8

  // one LDS pool, aliased views:
  //   K view:  [64][128] u16 (XOR-16 swizzled)
  //   Vt view: [128][72] u16
  //   epilogue: per-wave [32][136] u16 transpose buffer
  __shared__ __align__(16) u16 smem[64 * 128 + 128 * 72];   // 34816 B
  u16 (*K_lds)[128] = reinterpret_cast<u16(*)[128]>(smem);
  u16 (*Vt_lds)[72] = reinterpret_cast<u16(*)[72]>(smem + 64 * 128);

  // Q fragments: lane holds Q[q=l31][kc*16 + hi*8 .. +7] for kc=0..7
  bf16x8 qf[8];
  {
    const u16* qp = qws + ((size_t)b * NN + q0 + wv * 32 + l31) * CC + hi * 8;
#pragma unroll
    for (int kc = 0; kc < 8; ++kc) qf[kc] = *reinterpret_cast<const bf16x8*>(qp + kc * 16);
  }

  // staging geometry
  int kr[4], kc8[4], vc[4], vm8[4];
#pragma unroll
  for (int i = 0; i < 4; ++i) {
    int s = t + i * 256;
    kr[i] = s >> 4; kc8[i] = (s & 15) * 8;
    vc[i] = s >> 3; vm8[i] = (s & 7) * 8;
  }
  const u16* kg = kws + ((size_t)b * NN + seg * SEGLEN) * CC;
  const u16* vg = vws + (size_t)b * CC * NN + seg * SEGLEN;
  uint4 kreg[4], vreg[4];
#pragma unroll
  for (int i = 0; i < 4; ++i) kreg[i] = *reinterpret_cast<const uint4*>(kg + (size_t)kr[i] * CC + kc8[i]);
#pragma unroll
  for (int i = 0; i < 4; ++i) vreg[i] = *reinterpret_cast<const uint4*>(vg + (size_t)vc[i] * NN + vm8[i]);

  f32x16 yt[4];
#pragma unroll
  for (int ct = 0; ct < 4; ++ct)
#pragma unroll
    for (int r = 0; r < 16; ++r) yt[ct][r] = 0.f;
  float m_run = -1e30f, l_run = 0.f;

  for (int ch = 0; ch < NCH; ++ch) {
    __syncthreads();
#pragma unroll
    for (int i = 0; i < 4; ++i)
      *reinterpret_cast<uint4*>(&K_lds[kr[i]][kc8[i] ^ ((kr[i] & 15) * 8)]) = kreg[i];
#pragma unroll
    for (int i = 0; i < 4; ++i) *reinterpret_cast<uint4*>(&Vt_lds[vc[i]][vm8[i]]) = vreg[i];
    if (ch + 1 < NCH) {   // prefetch next chunk under compute
      kg += KVBLK * CC; vg += KVBLK;
#pragma unroll
      for (int i = 0; i < 4; ++i) kreg[i] = *reinterpret_cast<const uint4*>(kg + (size_t)kr[i] * CC + kc8[i]);
#pragma unroll
      for (int i = 0; i < 4; ++i) vreg[i] = *reinterpret_cast<const uint4*>(vg + (size_t)vc[i] * NN + vm8[i]);
    }
    __syncthreads();

    // --- swapped QK^T
    f32x16 st0, st1;
#pragma unroll
    for (int r = 0; r < 16; ++r) { st0[r] = 0.f; st1[r] = 0.f; }
    __builtin_amdgcn_s_setprio(1);
#pragma unroll
    for (int kc = 0; kc < 8; ++kc) {
      bf16x8 a0 = ldfrag(&K_lds[l31][(kc * 16 + hi * 8) ^ ((l31 & 15) * 8)]);
      bf16x8 a1 = ldfrag(&K_lds[32 + l31][(kc * 16 + hi * 8) ^ ((l31 & 15) * 8)]);
      st0 = mfma32(a0, qf[kc], st0);
      st1 = mfma32(a1, qf[kc], st1);
    }
    __builtin_amdgcn_s_setprio(0);

    // --- online softmax, tree reductions
    float tm[16];
#pragma unroll
    for (int i = 0; i < 16; ++i) tm[i] = fmaxf(st0[i], st1[i]);
#pragma unroll
    for (int i = 0; i < 8; ++i) tm[i] = fmaxf(tm[i], tm[i + 8]);
#pragma unroll
    for (int i = 0; i < 4; ++i) tm[i] = fmaxf(tm[i], tm[i + 4]);
    float mx = fmaxf(fmaxf(tm[0], tm[1]), fmaxf(tm[2], tm[3]));
    {
      v2i rr = __builtin_amdgcn_permlane32_swap(__float_as_int(mx), __float_as_int(mx), false, false);
      mx = fmaxf(__int_as_float(rr.x), __int_as_float(rr.y));
    }
    if (!__all(mx - m_run <= 8.f)) {   // defer-max
      float mnew = fmaxf(m_run, mx);
      float sc = __expf(m_run - mnew);
      l_run *= sc;
#pragma unroll
      for (int ct = 0; ct < 4; ++ct)
#pragma unroll
        for (int r = 0; r < 16; ++r) yt[ct][r] *= sc;
      m_run = mnew;
    }
#pragma unroll
    for (int r = 0; r < 16; ++r) st0[r] = __expf(st0[r] - m_run);
#pragma unroll
    for (int r = 0; r < 16; ++r) st1[r] = __expf(st1[r] - m_run);
    float ts[16];
#pragma unroll
    for (int i = 0; i < 16; ++i) ts[i] = st0[i] + st1[i];
#pragma unroll
    for (int i = 0; i < 8; ++i) ts[i] = ts[i] + ts[i + 8];
#pragma unroll
    for (int i = 0; i < 4; ++i) ts[i] = ts[i] + ts[i + 4];
    float ps = (ts[0] + ts[1]) + (ts[2] + ts[3]);
    {
      v2i rr = __builtin_amdgcn_permlane32_swap(__float_as_int(ps), __float_as_int(ps), false, false);
      ps = __int_as_float(rr.x) + __int_as_float(rr.y);
    }
    l_run += ps;

    // --- PV via cvt_pk + permlane32_swap (T12)
    __builtin_amdgcn_s_setprio(1);
#define PV_KC2(SS, KC2) do {                                                        \
      u32 X0 = cvtpk(SS[(((KC2)&1)*8)+0], SS[(((KC2)&1)*8)+1]);                     \
      u32 X1 = cvtpk(SS[(((KC2)&1)*8)+2], SS[(((KC2)&1)*8)+3]);                     \
      u32 X4 = cvtpk(SS[(((KC2)&1)*8)+4], SS[(((KC2)&1)*8)+5]);                     \
      u32 X5 = cvtpk(SS[(((KC2)&1)*8)+6], SS[(((KC2)&1)*8)+7]);                     \
      v2i s1 = __builtin_amdgcn_permlane32_swap((int)X0, (int)X4, false, false);    \
      v2i s2 = __builtin_amdgcn_permlane32_swap((int)X1, (int)X5, false, false);    \
      int4 bw = make_int4(s1.x, s2.x, s1.y, s2.y);                                  \
      bf16x8 pb = *reinterpret_cast<bf16x8*>(&bw);                                  \
      _Pragma("unroll")                                                             \
      for (int ct = 0; ct < 4; ++ct) {                                              \
        bf16x8 va = ldfrag(&Vt_lds[ct * 32 + l31][(KC2) * 16 + hi * 8]);            \
        yt[ct] = mfma32(va, pb, yt[ct]);                                            \
      }                                                                             \
    } while (0)
    PV_KC2(st0, 0);
    PV_KC2(st0, 1);
    PV_KC2(st1, 2);
    PV_KC2(st1, 3);
#undef PV_KC2
    __builtin_amdgcn_s_setprio(0);
  }

  // --- epilogue: transpose via per-wave LDS buffer, then coalesced stores.
  __syncthreads();   // all waves done reading K/Vt views
  const float inv_l = 1.0f / l_run;
  u16* eps = smem + wv * (32 * 136);   // per-wave [32 q][136 c-pitch]
#pragma unroll
  for (int ct = 0; ct < 4; ++ct)
#pragma unroll
    for (int g = 0; g < 4; ++g) {
      u32 w0 = cvtpk(yt[ct][4 * g + 0] * inv_l, yt[ct][4 * g + 1] * inv_l);
      u32 w1 = cvtpk(yt[ct][4 * g + 2] * inv_l, yt[ct][4 * g + 3] * inv_l);
      // c = ct*32 + g*8 + hi*4 + (0..3), q-row = l31
      *reinterpret_cast<uint2*>(&eps[l31 * 136 + ct * 32 + g * 8 + hi * 4]) = make_uint2(w0, w1);
    }
  __syncthreads();
  // read back rows and store coalesced: 4 q-rows (1 KB contiguous) per pass
  u16* yp_base = yacc + ((size_t)grp * NN + q0 + wv * 32) * CC;
#pragma unroll
  for (int pass = 0; pass < 8; ++pass) {
    int q_r = pass * 4 + (l >> 4);
    int cchunk = (l & 15) * 8;
    uint4 v = *reinterpret_cast<const uint4*>(&eps[q_r * 136 + cchunk]);
    *reinterpret_cast<uint4*>(yp_base + (size_t)q_r * CC + cchunk) = v;
  }
  if (l < 32) {
    const size_t row_g = (size_t)grp * NN + q0 + wv * 32 + l31;
    ml[row_g * 2 + 0] = m_run;
    ml[row_g * 2 + 1] = l_run;
  }
}

// ---------------------------------------------------------------------------
// Kernel 3: fused combine + out-projection.
// Stage y-tile from 8 bf16 partials (weighted by e^{m_s-M} l_s), then GEMM.
// out f32 [B][C][N]
// ---------------------------------------------------------------------------
__global__ __launch_bounds__(256) void outproj_kernel(
    const u16* __restrict__ yacc, const float* __restrict__ ml,
    const float* __restrict__ Ww, const float* __restrict__ Wb,
    float* __restrict__ out)
{
  const int t = threadIdx.x;
  const int nt0 = blockIdx.x * 64;
  const int b = blockIdx.y;

  __shared__ __align__(16) u16 W_lds[128][136];
  __shared__ __align__(16) u16 y_lds[64][136];

  for (int i = 0; i < 16; ++i) {
    int s = t + i * 256;
    int row = s >> 5, c4 = s & 31;
    float4 v = *reinterpret_cast<const float4*>(Ww + row * 128 + c4 * 4);
    u32 lo = (u32)f2bf(v.x) | ((u32)f2bf(v.y) << 16);
    u32 hi = (u32)f2bf(v.z) | ((u32)f2bf(v.w) << 16);
    *reinterpret_cast<uint2*>(&W_lds[row][c4 * 4]) = make_uint2(lo, hi);
  }
  // combine 8 segments while staging y
#pragma unroll
  for (int pass = 0; pass < 4; ++pass) {
    int row = pass * 16 + (t >> 4);
    int li = t & 15;
    int n = nt0 + row;
    float m_s[NSEG], l_s[NSEG];
#pragma unroll
    for (int s = 0; s < NSEG; ++s) {
      size_t rg = ((size_t)(b * NSEG + s) * NN + n);
      m_s[s] = ml[rg * 2];
      l_s[s] = ml[rg * 2 + 1];
    }
    float tm[4];
#pragma unroll
    for (int i = 0; i < 4; ++i) tm[i] = fmaxf(m_s[i], m_s[i + 4]);
    float M = fmaxf(fmaxf(tm[0], tm[1]), fmaxf(tm[2], tm[3]));
    float wgt[NSEG], Wsum = 0.f;
#pragma unroll
    for (int s = 0; s < NSEG; ++s) { wgt[s] = __expf(m_s[s] - M) * l_s[s]; Wsum += wgt[s]; }
    float inv = 1.0f / Wsum;
    float o[8];
#pragma unroll
    for (int j = 0; j < 8; ++j) o[j] = 0.f;
#pragma unroll
    for (int s = 0; s < NSEG; ++s) {
      uint4 v = *reinterpret_cast<const uint4*>(
          yacc + ((size_t)(b * NSEG + s) * NN + n) * CC + li * 8);
      const u16* h = reinterpret_cast<const u16*>(&v);
      float w = wgt[s];
#pragma unroll
      for (int j = 0; j < 8; ++j) o[j] += w * bf2f(h[j]);
    }
    u32 p0 = (u32)f2bf(o[0] * inv) | ((u32)f2bf(o[1] * inv) << 16);
    u32 p1 = (u32)f2bf(o[2] * inv) | ((u32)f2bf(o[3] * inv) << 16);
    u32 p2 = (u32)f2bf(o[4] * inv) | ((u32)f2bf(o[5] * inv) << 16);
    u32 p3 = (u32)f2bf(o[6] * inv) | ((u32)f2bf(o[7] * inv) << 16);
    *reinterpret_cast<uint4*>(&y_lds[row][li * 8]) = make_uint4(p0, p1, p2, p3);
  }
  __syncthreads();

  const int w_id = t >> 6, l = t & 63;
  const int lr = l & 15, lh = l >> 4;

  f32x4 acc[2][4];
#pragma unroll
  for (int rt = 0; rt < 2; ++rt)
#pragma unroll
    for (int nt = 0; nt < 4; ++nt) acc[rt][nt] = (f32x4){0.f, 0.f, 0.f, 0.f};
#pragma unroll
  for (int kc = 0; kc < 4; ++kc) {
    bf16x8 a0 = ldfrag(&W_lds[w_id * 32 + lr][kc * 32 + lh * 8]);
    bf16x8 a1 = ldfrag(&W_lds[w_id * 32 + 16 + lr][kc * 32 + lh * 8]);
#pragma unroll
    for (int nt = 0; nt < 4; ++nt) {
      bf16x8 bf = ldfrag(&y_lds[nt * 16 + lr][kc * 32 + lh * 8]);
      acc[0][nt] = mfma16(a0, bf, acc[0][nt]);
      acc[1][nt] = mfma16(a1, bf, acc[1][nt]);
    }
  }
#pragma unroll
  for (int rt = 0; rt < 2; ++rt)
#pragma unroll
    for (int r = 0; r < 4; ++r) {
      int c = w_id * 32 + rt * 16 + lh * 4 + r;
      float bv = Wb[c];
#pragma unroll
      for (int nt = 0; nt < 4; ++nt)
        out[((size_t)b * CC + c) * NN + nt0 + nt * 16 + lr] = acc[rt][nt][r] + bv;
    }
}

// ---------------------------------------------------------------------------
extern "C" void kernel_launch(void* const* d_in, const int* in_sizes, int n_in,
                              void* d_out, int out_size, void* d_ws, size_t ws_size,
                              hipStream_t stream) {
  const float* x0   = (const float*)d_in[0];
  const float* x1   = (const float*)d_in[1];
  const float* g_w  = (const float*)d_in[2];
  const float* g_b  = (const float*)d_in[3];
  const float* th_w = (const float*)d_in[4];
  const float* th_b = (const float*)d_in[5];
  const float* ph_w = (const float*)d_in[6];
  const float* ph_b = (const float*)d_in[7];
  const float* Ww   = (const float*)d_in[8];
  const float* Wb   = (const float*)d_in[9];

  char* ws = (char*)d_ws;
  // layout: q(4M) k(4M) v(4M) ml(1M) yacc_bf16(32M) = 45M total
  u16* qws    = (u16*)(ws + 0);
  u16* kws    = (u16*)(ws + (size_t)4194304);
  u16* vws    = (u16*)(ws + (size_t)8388608);
  float* mlp  = (float*)(ws + (size_t)12582912);
  u16* yacc   = (u16*)(ws + (size_t)13631488);

  dim3 gp(64, 4, 3);
  proj_kernel<<<gp, 256, 0, stream>>>(x0, x1, g_w, g_b, th_w, th_b, ph_w, ph_b,
                                      qws, kws, vws);
  dim3 ga(32, 4, NSEG);   // x fastest: consecutive blocks share K/V segment (L2 locality)
  attn_kernel<<<ga, 256, 0, stream>>>(qws, kws, vws, yacc, mlp);
  dim3 go(64, 4);
  outproj_kernel<<<go, 256, 0, stream>>>(yacc, mlp, Ww, Wb, (float*)d_out);
}

// Round 6
// 106.398 us; speedup vs baseline: 1.7498x; 1.0362x over previous
//
#include <hip/hip_runtime.h>
#include <hip/hip_bf16.h>
#include <stdint.h>

// Problem constants
#define BB 4
#define CC 128
#define NN 4096
#define NSEG 8
#define SEGLEN (NN / NSEG)   // 512
#define KVBLK 64

typedef __bf16 bf16_t;
typedef bf16_t bf16x8 __attribute__((ext_vector_type(8)));
typedef float f32x4 __attribute__((ext_vector_type(4)));
typedef float f32x16 __attribute__((ext_vector_type(16)));
typedef int v2i __attribute__((ext_vector_type(2)));
typedef unsigned int u32;
typedef unsigned short u16;

__device__ __forceinline__ u16 f2bf(float f) {
  union { float f; u32 u; } v; v.f = f;
  u32 r = v.u + 0x7FFFu + ((v.u >> 16) & 1u);   // RNE
  return (u16)(r >> 16);
}
__device__ __forceinline__ float bf2f(u16 x) {
  union { u32 u; float f; } v; v.u = ((u32)x) << 16; return v.f;
}

__device__ __forceinline__ bf16x8 ldfrag(const u16* p) {
  return *reinterpret_cast<const bf16x8*>(p);   // ds_read_b128
}

__device__ __forceinline__ f32x4 mfma16(bf16x8 a, bf16x8 b, f32x4 c) {
  return __builtin_amdgcn_mfma_f32_16x16x32_bf16(a, b, c, 0, 0, 0);
}
__device__ __forceinline__ f32x16 mfma32(bf16x8 a, bf16x8 b, f32x16 c) {
  return __builtin_amdgcn_mfma_f32_32x32x16_bf16(a, b, c, 0, 0, 0);
}
__device__ __forceinline__ u32 cvtpk(float lo, float hi) {
  u32 d; asm("v_cvt_pk_bf16_f32 %0, %1, %2" : "=v"(d) : "v"(lo), "v"(hi)); return d;
}

// ---------------------------------------------------------------------------
// Kernel 1: projections (unchanged).
//   p=0: theta -> qws [B][N][C];  p=1: phi -> kws [B][N][C];  p=2: g -> vws [B][C][N]
// ---------------------------------------------------------------------------
__global__ __launch_bounds__(256) void proj_kernel(
    const float* __restrict__ x0, const float* __restrict__ x1,
    const float* __restrict__ g_w, const float* __restrict__ g_b,
    const float* __restrict__ th_w, const float* __restrict__ th_b,
    const float* __restrict__ ph_w, const float* __restrict__ ph_b,
    u16* __restrict__ qws, u16* __restrict__ kws, u16* __restrict__ vws)
{
  const int t = threadIdx.x;
  const int nt0 = blockIdx.x * 64;
  const int b = blockIdx.y;
  const int p = blockIdx.z;

  __shared__ __align__(16) u16 W_lds[128][136];
  __shared__ __align__(16) u16 xT_lds[64][136];

  const float* x    = (p == 0) ? x1 : x0;
  const float* w    = (p == 0) ? th_w : (p == 1) ? ph_w : g_w;
  const float* bias = (p == 0) ? th_b : (p == 1) ? ph_b : g_b;

  for (int i = 0; i < 16; ++i) {
    int s = t + i * 256;
    int row = s >> 5, c4 = s & 31;
    float4 v = *reinterpret_cast<const float4*>(w + row * 128 + c4 * 4);
    u32 lo = (u32)f2bf(v.x) | ((u32)f2bf(v.y) << 16);
    u32 hi = (u32)f2bf(v.z) | ((u32)f2bf(v.w) << 16);
    *reinterpret_cast<uint2*>(&W_lds[row][c4 * 4]) = make_uint2(lo, hi);
  }
  for (int i = 0; i < 8; ++i) {
    int s = t + i * 256;
    int cp = s >> 4;
    int nc = s & 15;
    float4 v = *reinterpret_cast<const float4*>(x + ((size_t)b * CC + cp) * NN + nt0 + nc * 4);
    xT_lds[nc * 4 + 0][cp] = f2bf(v.x);
    xT_lds[nc * 4 + 1][cp] = f2bf(v.y);
    xT_lds[nc * 4 + 2][cp] = f2bf(v.z);
    xT_lds[nc * 4 + 3][cp] = f2bf(v.w);
  }
  __syncthreads();

  const int w_id = t >> 6, l = t & 63;
  const int lr = l & 15, lh = l >> 4;

  if (p < 2) {
    f32x4 acc[8];
#pragma unroll
    for (int ct = 0; ct < 8; ++ct) acc[ct] = (f32x4){0.f, 0.f, 0.f, 0.f};
#pragma unroll
    for (int kc = 0; kc < 4; ++kc) {
      bf16x8 a = ldfrag(&xT_lds[w_id * 16 + lr][kc * 32 + lh * 8]);
#pragma unroll
      for (int ct = 0; ct < 8; ++ct) {
        bf16x8 bf = ldfrag(&W_lds[ct * 16 + lr][kc * 32 + lh * 8]);
        acc[ct] = mfma16(a, bf, acc[ct]);
      }
    }
    u16* outp = (p == 0) ? qws : kws;
#pragma unroll
    for (int ct = 0; ct < 8; ++ct) {
      float bv = bias[ct * 16 + lr];
#pragma unroll
      for (int r = 0; r < 4; ++r) {
        int n = nt0 + w_id * 16 + lh * 4 + r;
        outp[((size_t)b * NN + n) * CC + ct * 16 + lr] = f2bf(acc[ct][r] + bv);
      }
    }
  } else {
    f32x4 acc[2][4];
#pragma unroll
    for (int rt = 0; rt < 2; ++rt)
#pragma unroll
      for (int nt = 0; nt < 4; ++nt) acc[rt][nt] = (f32x4){0.f, 0.f, 0.f, 0.f};
#pragma unroll
    for (int kc = 0; kc < 4; ++kc) {
      bf16x8 a0 = ldfrag(&W_lds[w_id * 32 + lr][kc * 32 + lh * 8]);
      bf16x8 a1 = ldfrag(&W_lds[w_id * 32 + 16 + lr][kc * 32 + lh * 8]);
#pragma unroll
      for (int nt = 0; nt < 4; ++nt) {
        bf16x8 bf = ldfrag(&xT_lds[nt * 16 + lr][kc * 32 + lh * 8]);
        acc[0][nt] = mfma16(a0, bf, acc[0][nt]);
        acc[1][nt] = mfma16(a1, bf, acc[1][nt]);
      }
    }
#pragma unroll
    for (int rt = 0; rt < 2; ++rt)
#pragma unroll
      for (int r = 0; r < 4; ++r) {
        int c = w_id * 32 + rt * 16 + lh * 4 + r;
        float bv = bias[c];
#pragma unroll
        for (int nt = 0; nt < 4; ++nt) {
          vws[((size_t)b * CC + c) * NN + nt0 + nt * 16 + lr] = f2bf(acc[rt][nt][r] + bv);
        }
      }
  }
}

// ---------------------------------------------------------------------------
// Kernel 2: flash attention, 32x32 MFMA, swapped-QK^T, in-register softmax.
// Double-buffered K/V LDS + raw s_barrier + manual lgkmcnt: ONE barrier per
// chunk, prefetch loads stay in flight ACROSS the barrier (never drained —
// __syncthreads() would emit s_waitcnt vmcnt(0) and kill the pipeline).
// ---------------------------------------------------------------------------
__global__ __launch_bounds__(256, 2) void attn_kernel(
    const u16* __restrict__ qws, const u16* __restrict__ kws,
    const u16* __restrict__ vws, u16* __restrict__ yacc,
    float* __restrict__ ml)
{
  const int t = threadIdx.x, wv = t >> 6, l = t & 63;
  const int l31 = l & 31, hi = l >> 5;
  const int q0 = blockIdx.x * 128;
  const int b = blockIdx.y, seg = blockIdx.z;
  const int grp = b * NSEG + seg;
  constexpr int NCH = SEGLEN / KVBLK;   // 8

  // double-buffered LDS: K [2][64][128] (XOR-16 swizzled) + Vt [2][128][72]
  // = 69632 B. Epilogue reuses the front as 4 x [32][136] transpose buffers.
  __shared__ __align__(16) u16 smem[2 * 64 * 128 + 2 * 128 * 72];
  u16 (*K_lds)[64][128] = reinterpret_cast<u16(*)[64][128]>(smem);
  u16 (*Vt_lds)[128][72] = reinterpret_cast<u16(*)[128][72]>(smem + 2 * 64 * 128);

  // Q fragments: lane holds Q[q=l31][kc*16 + hi*8 .. +7] for kc=0..7
  bf16x8 qf[8];
  {
    const u16* qp = qws + ((size_t)b * NN + q0 + wv * 32 + l31) * CC + hi * 8;
#pragma unroll
    for (int kc = 0; kc < 8; ++kc) qf[kc] = *reinterpret_cast<const bf16x8*>(qp + kc * 16);
  }

  // staging geometry
  int kr[4], kc8[4], vc[4], vm8[4];
#pragma unroll
  for (int i = 0; i < 4; ++i) {
    int s = t + i * 256;
    kr[i] = s >> 4; kc8[i] = (s & 15) * 8;
    vc[i] = s >> 3; vm8[i] = (s & 7) * 8;
  }
  const u16* kg0 = kws + ((size_t)b * NN + seg * SEGLEN) * CC;
  const u16* vg0 = vws + (size_t)b * CC * NN + seg * SEGLEN;
  uint4 kreg[4], vreg[4];

#define LD(CH) do {                                                                  \
    const u16* kp_ = kg0 + (size_t)(CH) * KVBLK * CC;                                \
    const u16* vp_ = vg0 + (CH) * KVBLK;                                             \
    _Pragma("unroll")                                                                \
    for (int i = 0; i < 4; ++i) kreg[i] = *reinterpret_cast<const uint4*>(kp_ + (size_t)kr[i] * CC + kc8[i]); \
    _Pragma("unroll")                                                                \
    for (int i = 0; i < 4; ++i) vreg[i] = *reinterpret_cast<const uint4*>(vp_ + (size_t)vc[i] * NN + vm8[i]); \
  } while (0)

#define ST(BUF) do {                                                                 \
    _Pragma("unroll")                                                                \
    for (int i = 0; i < 4; ++i)                                                      \
      *reinterpret_cast<uint4*>(&K_lds[BUF][kr[i]][kc8[i] ^ ((kr[i] & 15) * 8)]) = kreg[i]; \
    _Pragma("unroll")                                                                \
    for (int i = 0; i < 4; ++i)                                                      \
      *reinterpret_cast<uint4*>(&Vt_lds[BUF][vc[i]][vm8[i]]) = vreg[i];              \
  } while (0)

#define BARRIER_LGKM() do {                                                          \
    asm volatile("s_waitcnt lgkmcnt(0)" ::: "memory");                               \
    __builtin_amdgcn_sched_barrier(0);                                               \
    __builtin_amdgcn_s_barrier();                                                    \
    __builtin_amdgcn_sched_barrier(0);                                               \
  } while (0)

  f32x16 yt[4];
#pragma unroll
  for (int ct = 0; ct < 4; ++ct)
#pragma unroll
    for (int r = 0; r < 16; ++r) yt[ct][r] = 0.f;
  float m_run = -1e30f, l_run = 0.f;

  // prologue: stage chunk 0, issue chunk-1 loads, sync once
  LD(0);
  ST(0);        // compiler inserts the vmcnt dep-wait for kreg/vreg
  LD(1);        // stays in flight across the barrier
  BARRIER_LGKM();

  for (int ch = 0; ch < NCH; ++ch) {
    const int cur = ch & 1;
    const u16 (*Kb)[128] = K_lds[cur];
    const u16 (*Vb)[72]  = Vt_lds[cur];

    // --- swapped QK^T
    f32x16 st0, st1;
#pragma unroll
    for (int r = 0; r < 16; ++r) { st0[r] = 0.f; st1[r] = 0.f; }
    __builtin_amdgcn_s_setprio(1);
#pragma unroll
    for (int kc = 0; kc < 8; ++kc) {
      bf16x8 a0 = ldfrag(&Kb[l31][(kc * 16 + hi * 8) ^ ((l31 & 15) * 8)]);
      bf16x8 a1 = ldfrag(&Kb[32 + l31][(kc * 16 + hi * 8) ^ ((l31 & 15) * 8)]);
      st0 = mfma32(a0, qf[kc], st0);
      st1 = mfma32(a1, qf[kc], st1);
    }
    __builtin_amdgcn_s_setprio(0);

    // --- online softmax, tree reductions
    float tm[16];
#pragma unroll
    for (int i = 0; i < 16; ++i) tm[i] = fmaxf(st0[i], st1[i]);
#pragma unroll
    for (int i = 0; i < 8; ++i) tm[i] = fmaxf(tm[i], tm[i + 8]);
#pragma unroll
    for (int i = 0; i < 4; ++i) tm[i] = fmaxf(tm[i], tm[i + 4]);
    float mx = fmaxf(fmaxf(tm[0], tm[1]), fmaxf(tm[2], tm[3]));
    {
      v2i rr = __builtin_amdgcn_permlane32_swap(__float_as_int(mx), __float_as_int(mx), false, false);
      mx = fmaxf(__int_as_float(rr.x), __int_as_float(rr.y));
    }
    if (!__all(mx - m_run <= 8.f)) {   // defer-max
      float mnew = fmaxf(m_run, mx);
      float sc = __expf(m_run - mnew);
      l_run *= sc;
#pragma unroll
      for (int ct = 0; ct < 4; ++ct)
#pragma unroll
        for (int r = 0; r < 16; ++r) yt[ct][r] *= sc;
      m_run = mnew;
    }
#pragma unroll
    for (int r = 0; r < 16; ++r) st0[r] = __expf(st0[r] - m_run);
#pragma unroll
    for (int r = 0; r < 16; ++r) st1[r] = __expf(st1[r] - m_run);
    float ts[16];
#pragma unroll
    for (int i = 0; i < 16; ++i) ts[i] = st0[i] + st1[i];
#pragma unroll
    for (int i = 0; i < 8; ++i) ts[i] = ts[i] + ts[i + 8];
#pragma unroll
    for (int i = 0; i < 4; ++i) ts[i] = ts[i] + ts[i + 4];
    float ps = (ts[0] + ts[1]) + (ts[2] + ts[3]);
    {
      v2i rr = __builtin_amdgcn_permlane32_swap(__float_as_int(ps), __float_as_int(ps), false, false);
      ps = __int_as_float(rr.x) + __int_as_float(rr.y);
    }
    l_run += ps;

    // --- PV via cvt_pk + permlane32_swap (T12)
    __builtin_amdgcn_s_setprio(1);
#define PV_KC2(SS, KC2) do {                                                        \
      u32 X0 = cvtpk(SS[(((KC2)&1)*8)+0], SS[(((KC2)&1)*8)+1]);                     \
      u32 X1 = cvtpk(SS[(((KC2)&1)*8)+2], SS[(((KC2)&1)*8)+3]);                     \
      u32 X4 = cvtpk(SS[(((KC2)&1)*8)+4], SS[(((KC2)&1)*8)+5]);                     \
      u32 X5 = cvtpk(SS[(((KC2)&1)*8)+6], SS[(((KC2)&1)*8)+7]);                     \
      v2i s1 = __builtin_amdgcn_permlane32_swap((int)X0, (int)X4, false, false);    \
      v2i s2 = __builtin_amdgcn_permlane32_swap((int)X1, (int)X5, false, false);    \
      int4 bw = make_int4(s1.x, s2.x, s1.y, s2.y);                                  \
      bf16x8 pb = *reinterpret_cast<bf16x8*>(&bw);                                  \
      _Pragma("unroll")                                                             \
      for (int ct = 0; ct < 4; ++ct) {                                              \
        bf16x8 va = ldfrag(&Vb[ct * 32 + l31][(KC2) * 16 + hi * 8]);                \
        yt[ct] = mfma32(va, pb, yt[ct]);                                            \
      }                                                                             \
    } while (0)
    PV_KC2(st0, 0);
    PV_KC2(st0, 1);
    PV_KC2(st1, 2);
    PV_KC2(st1, 3);
#undef PV_KC2
    __builtin_amdgcn_s_setprio(0);

    // --- stage next chunk into the other buffer; keep loads pipelined
    if (ch + 1 < NCH) {
      ST((ch + 1) & 1);            // dep-wait on LD(ch+1) regs (vmcnt), not a drain
      if (ch + 2 < NCH) LD(ch + 2);   // in flight across the barrier
      BARRIER_LGKM();              // one barrier per chunk, lgkm only
    }
  }
#undef LD
#undef ST
#undef BARRIER_LGKM

  // --- epilogue: transpose via per-wave LDS buffer, then coalesced stores.
  __syncthreads();   // full drain OK here (once): all waves done with K/V LDS
  const float inv_l = 1.0f / l_run;
  u16* eps = smem + wv * (32 * 136);   // per-wave [32 q][136 c-pitch]
#pragma unroll
  for (int ct = 0; ct < 4; ++ct)
#pragma unroll
    for (int g = 0; g < 4; ++g) {
      u32 w0 = cvtpk(yt[ct][4 * g + 0] * inv_l, yt[ct][4 * g + 1] * inv_l);
      u32 w1 = cvtpk(yt[ct][4 * g + 2] * inv_l, yt[ct][4 * g + 3] * inv_l);
      *reinterpret_cast<uint2*>(&eps[l31 * 136 + ct * 32 + g * 8 + hi * 4]) = make_uint2(w0, w1);
    }
  __syncthreads();
  u16* yp_base = yacc + ((size_t)grp * NN + q0 + wv * 32) * CC;
#pragma unroll
  for (int pass = 0; pass < 8; ++pass) {
    int q_r = pass * 4 + (l >> 4);
    int cchunk = (l & 15) * 8;
    uint4 v = *reinterpret_cast<const uint4*>(&eps[q_r * 136 + cchunk]);
    *reinterpret_cast<uint4*>(yp_base + (size_t)q_r * CC + cchunk) = v;
  }
  if (l < 32) {
    const size_t row_g = (size_t)grp * NN + q0 + wv * 32 + l31;
    ml[row_g * 2 + 0] = m_run;
    ml[row_g * 2 + 1] = l_run;
  }
}

// ---------------------------------------------------------------------------
// Kernel 3: fused combine + out-projection (unchanged).
// ---------------------------------------------------------------------------
__global__ __launch_bounds__(256) void outproj_kernel(
    const u16* __restrict__ yacc, const float* __restrict__ ml,
    const float* __restrict__ Ww, const float* __restrict__ Wb,
    float* __restrict__ out)
{
  const int t = threadIdx.x;
  const int nt0 = blockIdx.x * 64;
  const int b = blockIdx.y;

  __shared__ __align__(16) u16 W_lds[128][136];
  __shared__ __align__(16) u16 y_lds[64][136];

  for (int i = 0; i < 16; ++i) {
    int s = t + i * 256;
    int row = s >> 5, c4 = s & 31;
    float4 v = *reinterpret_cast<const float4*>(Ww + row * 128 + c4 * 4);
    u32 lo = (u32)f2bf(v.x) | ((u32)f2bf(v.y) << 16);
    u32 hi = (u32)f2bf(v.z) | ((u32)f2bf(v.w) << 16);
    *reinterpret_cast<uint2*>(&W_lds[row][c4 * 4]) = make_uint2(lo, hi);
  }
  // combine 8 segments while staging y
#pragma unroll
  for (int pass = 0; pass < 4; ++pass) {
    int row = pass * 16 + (t >> 4);
    int li = t & 15;
    int n = nt0 + row;
    float m_s[NSEG], l_s[NSEG];
#pragma unroll
    for (int s = 0; s < NSEG; ++s) {
      size_t rg = ((size_t)(b * NSEG + s) * NN + n);
      m_s[s] = ml[rg * 2];
      l_s[s] = ml[rg * 2 + 1];
    }
    float tm[4];
#pragma unroll
    for (int i = 0; i < 4; ++i) tm[i] = fmaxf(m_s[i], m_s[i + 4]);
    float M = fmaxf(fmaxf(tm[0], tm[1]), fmaxf(tm[2], tm[3]));
    float wgt[NSEG], Wsum = 0.f;
#pragma unroll
    for (int s = 0; s < NSEG; ++s) { wgt[s] = __expf(m_s[s] - M) * l_s[s]; Wsum += wgt[s]; }
    float inv = 1.0f / Wsum;
    float o[8];
#pragma unroll
    for (int j = 0; j < 8; ++j) o[j] = 0.f;
#pragma unroll
    for (int s = 0; s < NSEG; ++s) {
      uint4 v = *reinterpret_cast<const uint4*>(
          yacc + ((size_t)(b * NSEG + s) * NN + n) * CC + li * 8);
      const u16* h = reinterpret_cast<const u16*>(&v);
      float w = wgt[s];
#pragma unroll
      for (int j = 0; j < 8; ++j) o[j] += w * bf2f(h[j]);
    }
    u32 p0 = (u32)f2bf(o[0] * inv) | ((u32)f2bf(o[1] * inv) << 16);
    u32 p1 = (u32)f2bf(o[2] * inv) | ((u32)f2bf(o[3] * inv) << 16);
    u32 p2 = (u32)f2bf(o[4] * inv) | ((u32)f2bf(o[5] * inv) << 16);
    u32 p3 = (u32)f2bf(o[6] * inv) | ((u32)f2bf(o[7] * inv) << 16);
    *reinterpret_cast<uint4*>(&y_lds[row][li * 8]) = make_uint4(p0, p1, p2, p3);
  }
  __syncthreads();

  const int w_id = t >> 6, l = t & 63;
  const int lr = l & 15, lh = l >> 4;

  f32x4 acc[2][4];
#pragma unroll
  for (int rt = 0; rt < 2; ++rt)
#pragma unroll
    for (int nt = 0; nt < 4; ++nt) acc[rt][nt] = (f32x4){0.f, 0.f, 0.f, 0.f};
#pragma unroll
  for (int kc = 0; kc < 4; ++kc) {
    bf16x8 a0 = ldfrag(&W_lds[w_id * 32 + lr][kc * 32 + lh * 8]);
    bf16x8 a1 = ldfrag(&W_lds[w_id * 32 + 16 + lr][kc * 32 + lh * 8]);
#pragma unroll
    for (int nt = 0; nt < 4; ++nt) {
      bf16x8 bf = ldfrag(&y_lds[nt * 16 + lr][kc * 32 + lh * 8]);
      acc[0][nt] = mfma16(a0, bf, acc[0][nt]);
      acc[1][nt] = mfma16(a1, bf, acc[1][nt]);
    }
  }
#pragma unroll
  for (int rt = 0; rt < 2; ++rt)
#pragma unroll
    for (int r = 0; r < 4; ++r) {
      int c = w_id * 32 + rt * 16 + lh * 4 + r;
      float bv = Wb[c];
#pragma unroll
      for (int nt = 0; nt < 4; ++nt)
        out[((size_t)b * CC + c) * NN + nt0 + nt * 16 + lr] = acc[rt][nt][r] + bv;
    }
}

// ---------------------------------------------------------------------------
extern "C" void kernel_launch(void* const* d_in, const int* in_sizes, int n_in,
                              void* d_out, int out_size, void* d_ws, size_t ws_size,
                              hipStream_t stream) {
  const float* x0   = (const float*)d_in[0];
  const float* x1   = (const float*)d_in[1];
  const float* g_w  = (const float*)d_in[2];
  const float* g_b  = (const float*)d_in[3];
  const float* th_w = (const float*)d_in[4];
  const float* th_b = (const float*)d_in[5];
  const float* ph_w = (const float*)d_in[6];
  const float* ph_b = (const float*)d_in[7];
  const float* Ww   = (const float*)d_in[8];
  const float* Wb   = (const float*)d_in[9];

  char* ws = (char*)d_ws;
  // layout: q(4M) k(4M) v(4M) ml(1M) yacc_bf16(32M) = 45M total
  u16* qws    = (u16*)(ws + 0);
  u16* kws    = (u16*)(ws + (size_t)4194304);
  u16* vws    = (u16*)(ws + (size_t)8388608);
  float* mlp  = (float*)(ws + (size_t)12582912);
  u16* yacc   = (u16*)(ws + (size_t)13631488);

  dim3 gp(64, 4, 3);
  proj_kernel<<<gp, 256, 0, stream>>>(x0, x1, g_w, g_b, th_w, th_b, ph_w, ph_b,
                                      qws, kws, vws);
  dim3 ga(32, 4, NSEG);   // x fastest: consecutive blocks share K/V segment (L2 locality)
  attn_kernel<<<ga, 256, 0, stream>>>(qws, kws, vws, yacc, mlp);
  dim3 go(64, 4);
  outproj_kernel<<<go, 256, 0, stream>>>(yacc, mlp, Ww, Wb, (float*)d_out);
}

// Round 7
// 81.551 us; speedup vs baseline: 2.2829x; 1.3047x over previous
//
#include <hip/hip_runtime.h>
#include <hip/hip_bf16.h>
#include <stdint.h>

// Problem constants
#define BB 4
#define CC 128
#define NN 4096
#define NSEG 8
#define SEGLEN (NN / NSEG)   // 512
#define KVBLK 32             // chunk of 32 keys; K buf 8KB, V buf 8KB

typedef __bf16 bf16_t;
typedef bf16_t bf16x8 __attribute__((ext_vector_type(8)));
typedef float f32x4 __attribute__((ext_vector_type(4)));
typedef float f32x16 __attribute__((ext_vector_type(16)));
typedef int v2i __attribute__((ext_vector_type(2)));
typedef unsigned int u32;
typedef unsigned short u16;

__device__ __forceinline__ u16 f2bf(float f) {
  union { float f; u32 u; } v; v.f = f;
  u32 r = v.u + 0x7FFFu + ((v.u >> 16) & 1u);   // RNE
  return (u16)(r >> 16);
}
__device__ __forceinline__ float bf2f(u16 x) {
  union { u32 u; float f; } v; v.u = ((u32)x) << 16; return v.f;
}

__device__ __forceinline__ bf16x8 ldfrag(const u16* p) {
  return *reinterpret_cast<const bf16x8*>(p);   // ds_read_b128
}

__device__ __forceinline__ f32x4 mfma16(bf16x8 a, bf16x8 b, f32x4 c) {
  return __builtin_amdgcn_mfma_f32_16x16x32_bf16(a, b, c, 0, 0, 0);
}
__device__ __forceinline__ f32x16 mfma32(bf16x8 a, bf16x8 b, f32x16 c) {
  return __builtin_amdgcn_mfma_f32_32x32x16_bf16(a, b, c, 0, 0, 0);
}
__device__ __forceinline__ u32 cvtpk(float lo, float hi) {
  u32 d; asm("v_cvt_pk_bf16_f32 %0, %1, %2" : "=v"(d) : "v"(lo), "v"(hi)); return d;
}

// direct global->LDS DMA, 16B per lane; LDS dest = wave-uniform base + lane*16
__device__ __forceinline__ void async_cp16(const void* g, void* l) {
  __builtin_amdgcn_global_load_lds(
      (const __attribute__((address_space(1))) void*)g,
      (__attribute__((address_space(3))) void*)l, 16, 0, 0);
}

// ---------------------------------------------------------------------------
// Kernel 1: projections (unchanged).
//   p=0: theta -> qws [B][N][C];  p=1: phi -> kws [B][N][C];  p=2: g -> vws [B][C][N]
// ---------------------------------------------------------------------------
__global__ __launch_bounds__(256) void proj_kernel(
    const float* __restrict__ x0, const float* __restrict__ x1,
    const float* __restrict__ g_w, const float* __restrict__ g_b,
    const float* __restrict__ th_w, const float* __restrict__ th_b,
    const float* __restrict__ ph_w, const float* __restrict__ ph_b,
    u16* __restrict__ qws, u16* __restrict__ kws, u16* __restrict__ vws)
{
  const int t = threadIdx.x;
  const int nt0 = blockIdx.x * 64;
  const int b = blockIdx.y;
  const int p = blockIdx.z;

  __shared__ __align__(16) u16 W_lds[128][136];
  __shared__ __align__(16) u16 xT_lds[64][136];

  const float* x    = (p == 0) ? x1 : x0;
  const float* w    = (p == 0) ? th_w : (p == 1) ? ph_w : g_w;
  const float* bias = (p == 0) ? th_b : (p == 1) ? ph_b : g_b;

  for (int i = 0; i < 16; ++i) {
    int s = t + i * 256;
    int row = s >> 5, c4 = s & 31;
    float4 v = *reinterpret_cast<const float4*>(w + row * 128 + c4 * 4);
    u32 lo = (u32)f2bf(v.x) | ((u32)f2bf(v.y) << 16);
    u32 hi = (u32)f2bf(v.z) | ((u32)f2bf(v.w) << 16);
    *reinterpret_cast<uint2*>(&W_lds[row][c4 * 4]) = make_uint2(lo, hi);
  }
  for (int i = 0; i < 8; ++i) {
    int s = t + i * 256;
    int cp = s >> 4;
    int nc = s & 15;
    float4 v = *reinterpret_cast<const float4*>(x + ((size_t)b * CC + cp) * NN + nt0 + nc * 4);
    xT_lds[nc * 4 + 0][cp] = f2bf(v.x);
    xT_lds[nc * 4 + 1][cp] = f2bf(v.y);
    xT_lds[nc * 4 + 2][cp] = f2bf(v.z);
    xT_lds[nc * 4 + 3][cp] = f2bf(v.w);
  }
  __syncthreads();

  const int w_id = t >> 6, l = t & 63;
  const int lr = l & 15, lh = l >> 4;

  if (p < 2) {
    f32x4 acc[8];
#pragma unroll
    for (int ct = 0; ct < 8; ++ct) acc[ct] = (f32x4){0.f, 0.f, 0.f, 0.f};
#pragma unroll
    for (int kc = 0; kc < 4; ++kc) {
      bf16x8 a = ldfrag(&xT_lds[w_id * 16 + lr][kc * 32 + lh * 8]);
#pragma unroll
      for (int ct = 0; ct < 8; ++ct) {
        bf16x8 bf = ldfrag(&W_lds[ct * 16 + lr][kc * 32 + lh * 8]);
        acc[ct] = mfma16(a, bf, acc[ct]);
      }
    }
    u16* outp = (p == 0) ? qws : kws;
#pragma unroll
    for (int ct = 0; ct < 8; ++ct) {
      float bv = bias[ct * 16 + lr];
#pragma unroll
      for (int r = 0; r < 4; ++r) {
        int n = nt0 + w_id * 16 + lh * 4 + r;
        outp[((size_t)b * NN + n) * CC + ct * 16 + lr] = f2bf(acc[ct][r] + bv);
      }
    }
  } else {
    f32x4 acc[2][4];
#pragma unroll
    for (int rt = 0; rt < 2; ++rt)
#pragma unroll
      for (int nt = 0; nt < 4; ++nt) acc[rt][nt] = (f32x4){0.f, 0.f, 0.f, 0.f};
#pragma unroll
    for (int kc = 0; kc < 4; ++kc) {
      bf16x8 a0 = ldfrag(&W_lds[w_id * 32 + lr][kc * 32 + lh * 8]);
      bf16x8 a1 = ldfrag(&W_lds[w_id * 32 + 16 + lr][kc * 32 + lh * 8]);
#pragma unroll
      for (int nt = 0; nt < 4; ++nt) {
        bf16x8 bf = ldfrag(&xT_lds[nt * 16 + lr][kc * 32 + lh * 8]);
        acc[0][nt] = mfma16(a0, bf, acc[0][nt]);
        acc[1][nt] = mfma16(a1, bf, acc[1][nt]);
      }
    }
#pragma unroll
    for (int rt = 0; rt < 2; ++rt)
#pragma unroll
      for (int r = 0; r < 4; ++r) {
        int c = w_id * 32 + rt * 16 + lh * 4 + r;
        float bv = bias[c];
#pragma unroll
        for (int nt = 0; nt < 4; ++nt) {
          vws[((size_t)b * CC + c) * NN + nt0 + nt * 16 + lr] = f2bf(acc[rt][nt][r] + bv);
        }
      }
  }
}

// ---------------------------------------------------------------------------
// Kernel 2: flash attention, 32x32 MFMA, swapped-QK^T, in-register softmax.
// KVBLK=32, 3-buffer LDS rotation (24.6KB -> 4 blocks/CU), global_load_lds
// staging with pre-swizzled source, counted vmcnt(2), 2 raw barriers/chunk
// (zero lgkm drains: no ds_writes exist in the loop).
// ---------------------------------------------------------------------------
__global__ __launch_bounds__(256, 4) void attn_kernel(
    const u16* __restrict__ qws, const u16* __restrict__ kws,
    const u16* __restrict__ vws, u16* __restrict__ yacc,
    float* __restrict__ ml)
{
  const int t = threadIdx.x, wv = t >> 6, l = t & 63;
  const int l31 = l & 31, hi = l >> 5;
  const int q0 = blockIdx.x * 128;
  const int b = blockIdx.y, seg = blockIdx.z;
  const int grp = b * NSEG + seg;
  const int m_base = seg * SEGLEN;
  constexpr int NCH = SEGLEN / KVBLK;   // 16

  // 3 rotating 8KB buffers. K buf: [32 rows][16 x 16B chunks], chunk^=(row&15).
  // V buf: [128 rows][4 x 16B chunks], chunk^=(row&3). Epilogue reuses pool.
  __shared__ __align__(16) u16 smem[3 * 4096];
  char* sb = (char*)smem;

  // Q fragments: lane holds Q[q = q0+wv*32+l31][kc*16 + hi*8 .. +7], kc=0..7
  bf16x8 qf[8];
  {
    const u16* qp = qws + ((size_t)b * NN + q0 + wv * 32 + l31) * CC + hi * 8;
#pragma unroll
    for (int kc = 0; kc < 8; ++kc) qf[kc] = *reinterpret_cast<const bf16x8*>(qp + kc * 16);
  }

  // staging: per-lane pre-swizzled global byte offsets (rule #21: linear LDS
  // dest + inverse-swizzled source + swizzled read)
  const u32 koff = ((u32)(t >> 4)) * 256 + ((u32)((t & 15) ^ ((t >> 4) & 15))) * 16;
  const u32 voff = ((u32)(t >> 2)) * 8192 + ((u32)((t & 3) ^ ((t >> 2) & 3))) * 16;
  const char* kgb = (const char*)(kws + ((size_t)b * NN + m_base) * CC);
  const char* vgb = (const char*)(vws + (size_t)b * CC * NN) + (size_t)m_base * 2;

#define ISSUE_K(CH, BOFF) do {                                                   \
    async_cp16(kgb + (size_t)(CH) * 8192 + koff,        sb + (BOFF) + wv * 1024);            \
    async_cp16(kgb + (size_t)(CH) * 8192 + koff + 4096, sb + (BOFF) + wv * 1024 + 4096);     \
  } while (0)
#define ISSUE_V(CH, BOFF) do {                                                   \
    async_cp16(vgb + (size_t)(CH) * 64 + voff,          sb + (BOFF) + wv * 1024);            \
    async_cp16(vgb + (size_t)(CH) * 64 + voff + 524288, sb + (BOFF) + wv * 1024 + 4096);     \
  } while (0)
#define SCHED0() __builtin_amdgcn_sched_barrier(0)
#define BAR() do { SCHED0(); __builtin_amdgcn_s_barrier(); SCHED0(); } while (0)

  f32x16 yt[4];
#pragma unroll
  for (int ct = 0; ct < 4; ++ct)
#pragma unroll
    for (int r = 0; r < 16; ++r) yt[ct][r] = 0.f;
  float m_run = -1e30f, l_run = 0.f;
  f32x16 st;

#define QK_BLOCK(BK) do {                                                        \
    const u16* kb = (const u16*)(sb + (BK));                                     \
    _Pragma("unroll")                                                            \
    for (int r = 0; r < 16; ++r) st[r] = 0.f;                                    \
    __builtin_amdgcn_s_setprio(1);                                               \
    _Pragma("unroll")                                                            \
    for (int kc = 0; kc < 8; ++kc) {                                             \
      bf16x8 a = ldfrag(kb + l31 * 128 + (((kc * 2 + hi) ^ (l31 & 15)) * 8));    \
      st = mfma32(a, qf[kc], st);                                                \
    }                                                                            \
    __builtin_amdgcn_s_setprio(0);                                               \
  } while (0)

#define SOFTMAX_BLOCK() do {                                                     \
    float tm[8];                                                                 \
    _Pragma("unroll")                                                            \
    for (int i2 = 0; i2 < 8; ++i2) tm[i2] = fmaxf(st[i2], st[i2 + 8]);           \
    _Pragma("unroll")                                                            \
    for (int i2 = 0; i2 < 4; ++i2) tm[i2] = fmaxf(tm[i2], tm[i2 + 4]);           \
    float mx = fmaxf(fmaxf(tm[0], tm[1]), fmaxf(tm[2], tm[3]));                  \
    mx = fmaxf(mx, __shfl_xor(mx, 32));                                          \
    if (!__all(mx - m_run <= 8.f)) {                                             \
      float mnew = fmaxf(m_run, mx);                                             \
      float sc = __expf(m_run - mnew);                                           \
      l_run *= sc;                                                               \
      _Pragma("unroll")                                                          \
      for (int ct = 0; ct < 4; ++ct)                                             \
        _Pragma("unroll")                                                        \
        for (int r = 0; r < 16; ++r) yt[ct][r] *= sc;                            \
      m_run = mnew;                                                              \
    }                                                                            \
    _Pragma("unroll")                                                            \
    for (int r = 0; r < 16; ++r) st[r] = __expf(st[r] - m_run);                  \
    float ts[8];                                                                 \
    _Pragma("unroll")                                                            \
    for (int i2 = 0; i2 < 8; ++i2) ts[i2] = st[i2] + st[i2 + 8];                 \
    _Pragma("unroll")                                                            \
    for (int i2 = 0; i2 < 4; ++i2) ts[i2] = ts[i2] + ts[i2 + 4];                 \
    float ps = (ts[0] + ts[1]) + (ts[2] + ts[3]);                                \
    ps += __shfl_xor(ps, 32);                                                    \
    l_run += ps;                                                                 \
  } while (0)

#define PV_KS(VB, KS) do {                                                       \
    u32 X0 = cvtpk(st[((KS) & 1) * 8 + 0], st[((KS) & 1) * 8 + 1]);              \
    u32 X1 = cvtpk(st[((KS) & 1) * 8 + 2], st[((KS) & 1) * 8 + 3]);              \
    u32 X4 = cvtpk(st[((KS) & 1) * 8 + 4], st[((KS) & 1) * 8 + 5]);              \
    u32 X5 = cvtpk(st[((KS) & 1) * 8 + 6], st[((KS) & 1) * 8 + 7]);              \
    v2i s1 = __builtin_amdgcn_permlane32_swap((int)X0, (int)X4, false, false);   \
    v2i s2 = __builtin_amdgcn_permlane32_swap((int)X1, (int)X5, false, false);   \
    int4 bw = make_int4(s1.x, s2.x, s1.y, s2.y);                                 \
    bf16x8 pb = *reinterpret_cast<bf16x8*>(&bw);                                 \
    _Pragma("unroll")                                                            \
    for (int ct = 0; ct < 4; ++ct) {                                             \
      bf16x8 va = ldfrag((const u16*)(sb + (VB)) + (ct * 32 + l31) * 32 +        \
                         ((((KS) * 2 + hi) ^ (l31 & 3)) * 8));                   \
      yt[ct] = mfma32(va, pb, yt[ct]);                                           \
    }                                                                            \
  } while (0)

  // prologue: stage chunk 0 (K->buf0, V->buf1), drain, sync.
  u32 bK = 0, bV = 8192, bN = 16384;
  ISSUE_K(0, bK);
  ISSUE_V(0, bV);
  asm volatile("s_waitcnt vmcnt(0)" ::: "memory");
  BAR();

  for (int ch = 0; ch < NCH - 1; ++ch) {
    ISSUE_K(ch + 1, bN);               // into idle buffer; in flight across compute
    QK_BLOCK(bK);
    SOFTMAX_BLOCK();
    asm volatile("s_waitcnt vmcnt(2)" ::: "memory");   // drain V[ch], keep K[ch+1]
    BAR();                             // all waves: V[ch] ready, K buf free
    ISSUE_V(ch + 1, bK);               // V latency hides under next chunk's QK
    __builtin_amdgcn_s_setprio(1);
    PV_KS(bV, 0);
    PV_KS(bV, 1);
    __builtin_amdgcn_s_setprio(0);
    asm volatile("s_waitcnt vmcnt(2)" ::: "memory");   // drain K[ch+1], keep V[ch+1]
    BAR();
    u32 tmp = bK; bK = bN; bN = bV; bV = tmp;          // (k,v,n) <- (n,k,v)
  }
  // peeled last chunk
  QK_BLOCK(bK);
  SOFTMAX_BLOCK();
  asm volatile("s_waitcnt vmcnt(0)" ::: "memory");
  BAR();
  __builtin_amdgcn_s_setprio(1);
  PV_KS(bV, 0);
  PV_KS(bV, 1);
  __builtin_amdgcn_s_setprio(0);

#undef QK_BLOCK
#undef SOFTMAX_BLOCK
#undef PV_KS
#undef ISSUE_K
#undef ISSUE_V

  // --- epilogue: per-wave LDS transpose (2 half-passes; pool = 24.6KB),
  // then fully-coalesced bf16 stores of l-normalized partials.
  __syncthreads();   // full drain fine here (once)
  const float inv_l = 1.0f / l_run;
  if (l < 32) {
    const size_t row_g = (size_t)grp * NN + q0 + wv * 32 + l31;
    ml[row_g * 2 + 0] = m_run;
    ml[row_g * 2 + 1] = l_run;
  }
  u16* yp_base = yacc + ((size_t)grp * NN + q0 + wv * 32) * CC;
#pragma unroll
  for (int half = 0; half < 2; ++half) {
    if ((wv >> 1) == half) {
      u16* eps = smem + (wv & 1) * 4352;   // [32 q][136 c-pitch]
#pragma unroll
      for (int ct = 0; ct < 4; ++ct)
#pragma unroll
        for (int g = 0; g < 4; ++g) {
          u32 w0 = cvtpk(yt[ct][4 * g + 0] * inv_l, yt[ct][4 * g + 1] * inv_l);
          u32 w1 = cvtpk(yt[ct][4 * g + 2] * inv_l, yt[ct][4 * g + 3] * inv_l);
          *reinterpret_cast<uint2*>(&eps[l31 * 136 + ct * 32 + g * 8 + hi * 4]) = make_uint2(w0, w1);
        }
      // within-wave write->read; compiler inserts lgkm waits
#pragma unroll
      for (int pass = 0; pass < 8; ++pass) {
        int q_r = pass * 4 + (l >> 4);
        int cchunk = (l & 15) * 8;
        uint4 v = *reinterpret_cast<const uint4*>(&eps[q_r * 136 + cchunk]);
        *reinterpret_cast<uint4*>(yp_base + (size_t)q_r * CC + cchunk) = v;
      }
    }
    __syncthreads();
  }
}

// ---------------------------------------------------------------------------
// Kernel 3: fused combine + out-projection (unchanged, NSEG=8).
// ---------------------------------------------------------------------------
__global__ __launch_bounds__(256) void outproj_kernel(
    const u16* __restrict__ yacc, const float* __restrict__ ml,
    const float* __restrict__ Ww, const float* __restrict__ Wb,
    float* __restrict__ out)
{
  const int t = threadIdx.x;
  const int nt0 = blockIdx.x * 64;
  const int b = blockIdx.y;

  __shared__ __align__(16) u16 W_lds[128][136];
  __shared__ __align__(16) u16 y_lds[64][136];

  for (int i = 0; i < 16; ++i) {
    int s = t + i * 256;
    int row = s >> 5, c4 = s & 31;
    float4 v = *reinterpret_cast<const float4*>(Ww + row * 128 + c4 * 4);
    u32 lo = (u32)f2bf(v.x) | ((u32)f2bf(v.y) << 16);
    u32 hi = (u32)f2bf(v.z) | ((u32)f2bf(v.w) << 16);
    *reinterpret_cast<uint2*>(&W_lds[row][c4 * 4]) = make_uint2(lo, hi);
  }
  // combine 8 segments while staging y
#pragma unroll
  for (int pass = 0; pass < 4; ++pass) {
    int row = pass * 16 + (t >> 4);
    int li = t & 15;
    int n = nt0 + row;
    float m_s[NSEG], l_s[NSEG];
#pragma unroll
    for (int s = 0; s < NSEG; ++s) {
      size_t rg = ((size_t)(b * NSEG + s) * NN + n);
      m_s[s] = ml[rg * 2];
      l_s[s] = ml[rg * 2 + 1];
    }
    float tm[4];
#pragma unroll
    for (int i = 0; i < 4; ++i) tm[i] = fmaxf(m_s[i], m_s[i + 4]);
    float M = fmaxf(fmaxf(tm[0], tm[1]), fmaxf(tm[2], tm[3]));
    float wgt[NSEG], Wsum = 0.f;
#pragma unroll
    for (int s = 0; s < NSEG; ++s) { wgt[s] = __expf(m_s[s] - M) * l_s[s]; Wsum += wgt[s]; }
    float inv = 1.0f / Wsum;
    float o[8];
#pragma unroll
    for (int j = 0; j < 8; ++j) o[j] = 0.f;
#pragma unroll
    for (int s = 0; s < NSEG; ++s) {
      uint4 v = *reinterpret_cast<const uint4*>(
          yacc + ((size_t)(b * NSEG + s) * NN + n) * CC + li * 8);
      const u16* h = reinterpret_cast<const u16*>(&v);
      float w = wgt[s];
#pragma unroll
      for (int j = 0; j < 8; ++j) o[j] += w * bf2f(h[j]);
    }
    u32 p0 = (u32)f2bf(o[0] * inv) | ((u32)f2bf(o[1] * inv) << 16);
    u32 p1 = (u32)f2bf(o[2] * inv) | ((u32)f2bf(o[3] * inv) << 16);
    u32 p2 = (u32)f2bf(o[4] * inv) | ((u32)f2bf(o[5] * inv) << 16);
    u32 p3 = (u32)f2bf(o[6] * inv) | ((u32)f2bf(o[7] * inv) << 16);
    *reinterpret_cast<uint4*>(&y_lds[row][li * 8]) = make_uint4(p0, p1, p2, p3);
  }
  __syncthreads();

  const int w_id = t >> 6, l = t & 63;
  const int lr = l & 15, lh = l >> 4;

  f32x4 acc[2][4];
#pragma unroll
  for (int rt = 0; rt < 2; ++rt)
#pragma unroll
    for (int nt = 0; nt < 4; ++nt) acc[rt][nt] = (f32x4){0.f, 0.f, 0.f, 0.f};
#pragma unroll
  for (int kc = 0; kc < 4; ++kc) {
    bf16x8 a0 = ldfrag(&W_lds[w_id * 32 + lr][kc * 32 + lh * 8]);
    bf16x8 a1 = ldfrag(&W_lds[w_id * 32 + 16 + lr][kc * 32 + lh * 8]);
#pragma unroll
    for (int nt = 0; nt < 4; ++nt) {
      bf16x8 bf = ldfrag(&y_lds[nt * 16 + lr][kc * 32 + lh * 8]);
      acc[0][nt] = mfma16(a0, bf, acc[0][nt]);
      acc[1][nt] = mfma16(a1, bf, acc[1][nt]);
    }
  }
#pragma unroll
  for (int rt = 0; rt < 2; ++rt)
#pragma unroll
    for (int r = 0; r < 4; ++r) {
      int c = w_id * 32 + rt * 16 + lh * 4 + r;
      float bv = Wb[c];
#pragma unroll
      for (int nt = 0; nt < 4; ++nt)
        out[((size_t)b * CC + c) * NN + nt0 + nt * 16 + lr] = acc[rt][nt][r] + bv;
    }
}

// ---------------------------------------------------------------------------
extern "C" void kernel_launch(void* const* d_in, const int* in_sizes, int n_in,
                              void* d_out, int out_size, void* d_ws, size_t ws_size,
                              hipStream_t stream) {
  const float* x0   = (const float*)d_in[0];
  const float* x1   = (const float*)d_in[1];
  const float* g_w  = (const float*)d_in[2];
  const float* g_b  = (const float*)d_in[3];
  const float* th_w = (const float*)d_in[4];
  const float* th_b = (const float*)d_in[5];
  const float* ph_w = (const float*)d_in[6];
  const float* ph_b = (const float*)d_in[7];
  const float* Ww   = (const float*)d_in[8];
  const float* Wb   = (const float*)d_in[9];

  char* ws = (char*)d_ws;
  // layout: q(4M) k(4M) v(4M) ml(1M) yacc_bf16(32M) = 45M total
  u16* qws    = (u16*)(ws + 0);
  u16* kws    = (u16*)(ws + (size_t)4194304);
  u16* vws    = (u16*)(ws + (size_t)8388608);
  float* mlp  = (float*)(ws + (size_t)12582912);
  u16* yacc   = (u16*)(ws + (size_t)13631488);

  dim3 gp(64, 4, 3);
  proj_kernel<<<gp, 256, 0, stream>>>(x0, x1, g_w, g_b, th_w, th_b, ph_w, ph_b,
                                      qws, kws, vws);
  dim3 ga(32, 4, NSEG);   // x fastest: consecutive blocks share K/V segment (L2 locality)
  attn_kernel<<<ga, 256, 0, stream>>>(qws, kws, vws, yacc, mlp);
  dim3 go(64, 4);
  outproj_kernel<<<go, 256, 0, stream>>>(yacc, mlp, Ww, Wb, (float*)d_out);
}